// Round 1
// baseline (2498.878 us; speedup 1.0000x reference)
//
#include <hip/hip_runtime.h>
#include <math.h>

// Problem constants
#define B_ 8
#define N_ 2048
#define HD_ 512
#define H_ 8
#define M_ 128
#define VD_ 64
// LAM = 0.01, EPS = 0.002 ; LAM/EPS = 5 ; 1/EPS = 500 ; 1/(100*EPS^2) = 2500

// ---------------------------------------------------------------------------
// GEMM: Y[r,c] = sum_k X[r,k]*W[c,k] + bias[c], optional per-row scale (mask).
// R=16384, K=512, C=512. 128x128 tile, 256 threads, 8x8 per thread.
// ---------------------------------------------------------------------------
__global__ __launch_bounds__(256) void gemm_xwT(
    const float* __restrict__ X, const float* __restrict__ Wm,
    const float* __restrict__ bias, const float* __restrict__ rowscale,
    float* __restrict__ Y)
{
  __shared__ alignas(16) float As[16][128];
  __shared__ alignas(16) float Bs[16][128];
  const int tid = threadIdx.x;
  const int bx = blockIdx.x & 3;
  const int by = blockIdx.x >> 2;
  const int row0 = by << 7, col0 = bx << 7;
  const int ty = tid >> 4, tx = tid & 15;
  float acc[8][8];
#pragma unroll
  for (int i = 0; i < 8; ++i)
#pragma unroll
    for (int j = 0; j < 8; ++j) acc[i][j] = 0.f;

  const int lr = tid >> 1;
  const int lk = (tid & 1) << 3;

  for (int k0 = 0; k0 < 512; k0 += 16) {
    float4 a0 = *(const float4*)(X + (size_t)(row0 + lr) * 512 + k0 + lk);
    float4 a1 = *(const float4*)(X + (size_t)(row0 + lr) * 512 + k0 + lk + 4);
    float4 b0 = *(const float4*)(Wm + (size_t)(col0 + lr) * 512 + k0 + lk);
    float4 b1 = *(const float4*)(Wm + (size_t)(col0 + lr) * 512 + k0 + lk + 4);
    As[lk+0][lr] = a0.x; As[lk+1][lr] = a0.y; As[lk+2][lr] = a0.z; As[lk+3][lr] = a0.w;
    As[lk+4][lr] = a1.x; As[lk+5][lr] = a1.y; As[lk+6][lr] = a1.z; As[lk+7][lr] = a1.w;
    Bs[lk+0][lr] = b0.x; Bs[lk+1][lr] = b0.y; Bs[lk+2][lr] = b0.z; Bs[lk+3][lr] = b0.w;
    Bs[lk+4][lr] = b1.x; Bs[lk+5][lr] = b1.y; Bs[lk+6][lr] = b1.z; Bs[lk+7][lr] = b1.w;
    __syncthreads();
#pragma unroll
    for (int kk = 0; kk < 16; ++kk) {
      float4 av0 = *(const float4*)&As[kk][ty*8];
      float4 av1 = *(const float4*)&As[kk][ty*8+4];
      float4 bv0 = *(const float4*)&Bs[kk][tx*8];
      float4 bv1 = *(const float4*)&Bs[kk][tx*8+4];
      float a[8] = {av0.x, av0.y, av0.z, av0.w, av1.x, av1.y, av1.z, av1.w};
      float b[8] = {bv0.x, bv0.y, bv0.z, bv0.w, bv1.x, bv1.y, bv1.z, bv1.w};
#pragma unroll
      for (int i = 0; i < 8; ++i)
#pragma unroll
        for (int j = 0; j < 8; ++j) acc[i][j] = fmaf(a[i], b[j], acc[i][j]);
    }
    __syncthreads();
  }
#pragma unroll
  for (int i = 0; i < 8; ++i) {
    const int r = row0 + ty*8 + i;
    const float rs = rowscale ? rowscale[r] : 1.f;
#pragma unroll
    for (int j = 0; j < 8; j += 4) {
      const int c = col0 + tx*8 + j;
      float4 o;
      o.x = (acc[i][j+0] + bias[c+0]) * rs;
      o.y = (acc[i][j+1] + bias[c+1]) * rs;
      o.z = (acc[i][j+2] + bias[c+2]) * rs;
      o.w = (acc[i][j+3] + bias[c+3]) * rs;
      *(float4*)(Y + (size_t)r * 512 + c) = o;
    }
  }
}

// ---------------------------------------------------------------------------
// RFF: Phi[bh,n,m] = 0.125 * cos( sum_d Q[b,n,h*64+d]*omega[d,m] + brff[m] ) * mask[b,n]
// One block = 4 consecutive n of one (b,h); 128 threads = one m each.
// ---------------------------------------------------------------------------
__global__ __launch_bounds__(128) void rff_kernel(
    const float* __restrict__ Q, const float* __restrict__ omega,
    const float* __restrict__ brff, const float* __restrict__ mask,
    float* __restrict__ Phi)
{
  const int m = threadIdx.x;
  const int blk = blockIdx.x;
  const int nc = blk & 511;   // N/4 = 512
  const int bh = blk >> 9;
  const int b = bh >> 3, h = bh & 7;
  const int n0 = nc << 2;
  __shared__ float qs[4][64];
  {
    const int r = m >> 6, d = m & 63;
    qs[r][d]   = Q[((size_t)(b*N_) + n0 + r) * 512 + h*64 + d];
    qs[r+2][d] = Q[((size_t)(b*N_) + n0 + r + 2) * 512 + h*64 + d];
  }
  __syncthreads();
  float z0 = 0.f, z1 = 0.f, z2 = 0.f, z3 = 0.f;
#pragma unroll 4
  for (int d = 0; d < 64; ++d) {
    const float om = omega[d*M_ + m];
    z0 = fmaf(qs[0][d], om, z0);
    z1 = fmaf(qs[1][d], om, z1);
    z2 = fmaf(qs[2][d], om, z2);
    z3 = fmaf(qs[3][d], om, z3);
  }
  const float bm = brff[m];
  const float sc = 0.125f;  // sqrt(2/128)
  const size_t ob = ((size_t)bh * N_ + n0) * M_ + m;
  const int mb = b*N_ + n0;
  Phi[ob      ] = sc * cosf(z0 + bm) * mask[mb+0];
  Phi[ob + 128] = sc * cosf(z1 + bm) * mask[mb+1];
  Phi[ob + 256] = sc * cosf(z2 + bm) * mask[mb+2];
  Phi[ob + 384] = sc * cosf(z3 + bm) * mask[mb+3];
}

// ---------------------------------------------------------------------------
// Gram partial: Part[(sp*64+bh)*16384 + i*128+j] = sum_{n in split sp} Phi[n,i]*Phi[n,j]
// ---------------------------------------------------------------------------
__global__ __launch_bounds__(256) void gram_partial(
    const float* __restrict__ Phi, float* __restrict__ Part)
{
  const int bh = blockIdx.x, sp = blockIdx.y, tid = threadIdx.x;
  __shared__ alignas(16) float Ps[16][128];
  const int ty = tid >> 4, tx = tid & 15;
  float acc[8][8];
#pragma unroll
  for (int i = 0; i < 8; ++i)
#pragma unroll
    for (int j = 0; j < 8; ++j) acc[i][j] = 0.f;
  const int lrow = tid >> 4, lcol = (tid & 15) << 3;
  for (int n0 = sp*512; n0 < sp*512 + 512; n0 += 16) {
    float4 p0 = *(const float4*)(Phi + ((size_t)bh*N_ + n0 + lrow)*M_ + lcol);
    float4 p1 = *(const float4*)(Phi + ((size_t)bh*N_ + n0 + lrow)*M_ + lcol + 4);
    *(float4*)&Ps[lrow][lcol]   = p0;
    *(float4*)&Ps[lrow][lcol+4] = p1;
    __syncthreads();
#pragma unroll
    for (int kk = 0; kk < 16; ++kk) {
      float4 av0 = *(const float4*)&Ps[kk][ty*8];
      float4 av1 = *(const float4*)&Ps[kk][ty*8+4];
      float4 bv0 = *(const float4*)&Ps[kk][tx*8];
      float4 bv1 = *(const float4*)&Ps[kk][tx*8+4];
      float a[8] = {av0.x, av0.y, av0.z, av0.w, av1.x, av1.y, av1.z, av1.w};
      float b[8] = {bv0.x, bv0.y, bv0.z, bv0.w, bv1.x, bv1.y, bv1.z, bv1.w};
#pragma unroll
      for (int i = 0; i < 8; ++i)
#pragma unroll
        for (int j = 0; j < 8; ++j) acc[i][j] = fmaf(a[i], b[j], acc[i][j]);
    }
    __syncthreads();
  }
  const size_t ob = ((size_t)sp*64 + bh) * 16384;
#pragma unroll
  for (int i = 0; i < 8; ++i)
#pragma unroll
    for (int j = 0; j < 8; j += 4) {
      float4 o = {acc[i][j], acc[i][j+1], acc[i][j+2], acc[i][j+3]};
      *(float4*)(Part + ob + (size_t)(ty*8+i)*128 + tx*8 + j) = o;
    }
}

// ---------------------------------------------------------------------------
// PhiT V partial: Part[(sp*64+bh)*8192 + m*64+d] = sum_{n in split} Phi[n,m]*V[b,n,h*64+d]
// ---------------------------------------------------------------------------
__global__ __launch_bounds__(256) void phiTv_partial(
    const float* __restrict__ Phi, const float* __restrict__ V,
    float* __restrict__ Part)
{
  const int bh = blockIdx.x, sp = blockIdx.y, tid = threadIdx.x;
  const int b = bh >> 3, h = bh & 7;
  __shared__ alignas(16) float Ps[16][128];
  __shared__ alignas(16) float Vs[16][64];
  const int ty = tid >> 3, tx = tid & 7;  // ty 0..31 (rows m), tx 0..7 (cols d)
  float acc[4][8];
#pragma unroll
  for (int i = 0; i < 4; ++i)
#pragma unroll
    for (int j = 0; j < 8; ++j) acc[i][j] = 0.f;
  const int lrow = tid >> 4, lcol = (tid & 15) << 3;
  const int vrow = tid >> 3, vcol = (tid & 7) << 3;
  for (int n0 = sp*512; n0 < sp*512 + 512; n0 += 16) {
    float4 p0 = *(const float4*)(Phi + ((size_t)bh*N_ + n0 + lrow)*M_ + lcol);
    float4 p1 = *(const float4*)(Phi + ((size_t)bh*N_ + n0 + lrow)*M_ + lcol + 4);
    *(float4*)&Ps[lrow][lcol]   = p0;
    *(float4*)&Ps[lrow][lcol+4] = p1;
    if (tid < 128) {
      float4 v0 = *(const float4*)(V + ((size_t)(b*N_) + n0 + vrow)*512 + h*64 + vcol);
      float4 v1 = *(const float4*)(V + ((size_t)(b*N_) + n0 + vrow)*512 + h*64 + vcol + 4);
      *(float4*)&Vs[vrow][vcol]   = v0;
      *(float4*)&Vs[vrow][vcol+4] = v1;
    }
    __syncthreads();
#pragma unroll
    for (int kk = 0; kk < 16; ++kk) {
      float4 av = *(const float4*)&Ps[kk][ty*4];
      float4 bv0 = *(const float4*)&Vs[kk][tx*8];
      float4 bv1 = *(const float4*)&Vs[kk][tx*8+4];
      float a[4] = {av.x, av.y, av.z, av.w};
      float b[8] = {bv0.x, bv0.y, bv0.z, bv0.w, bv1.x, bv1.y, bv1.z, bv1.w};
#pragma unroll
      for (int i = 0; i < 4; ++i)
#pragma unroll
        for (int j = 0; j < 8; ++j) acc[i][j] = fmaf(a[i], b[j], acc[i][j]);
    }
    __syncthreads();
  }
  const size_t ob = ((size_t)sp*64 + bh) * 8192;
#pragma unroll
  for (int i = 0; i < 4; ++i)
#pragma unroll
    for (int j = 0; j < 8; j += 4) {
      float4 o = {acc[i][j], acc[i][j+1], acc[i][j+2], acc[i][j+3]};
      *(float4*)(Part + ob + (size_t)(ty*4+i)*64 + tx*8 + j) = o;
    }
}

// ---------------------------------------------------------------------------
// Sum 4 split partials
// ---------------------------------------------------------------------------
__global__ __launch_bounds__(256) void reduce4_kernel(
    const float* __restrict__ part, float* __restrict__ out, int n, size_t cs)
{
  const int i = blockIdx.x * 256 + threadIdx.x;
  if (i < n) out[i] = (part[i] + part[cs + i]) + (part[2*cs + i] + part[3*cs + i]);
}

// ---------------------------------------------------------------------------
// yy[bh] = sum_{n,d} v^2
// ---------------------------------------------------------------------------
__global__ __launch_bounds__(256) void yy_kernel(
    const float* __restrict__ V, float* __restrict__ yy)
{
  const int bh = blockIdx.x, tid = threadIdx.x;
  const int b = bh >> 3, h = bh & 7;
  float s = 0.f;
  for (int t = tid; t < N_*64; t += 256) {
    const int n = t >> 6, d = t & 63;
    const float v = V[((size_t)(b*N_) + n)*512 + h*64 + d];
    s = fmaf(v, v, s);
  }
  __shared__ float red[256];
  red[tid] = s; __syncthreads();
  for (int st = 128; st > 0; st >>= 1) {
    if (tid < st) red[tid] += red[tid+st];
    __syncthreads();
  }
  if (tid == 0) yy[bh] = red[0];
}

// ---------------------------------------------------------------------------
// 4 batched Cholesky factorizations per bh:
//   which 0: Ak = Gk + lam*I          -> Lk
//   which 1: Ao = Go + lam*I          -> Lo   (+logdet)
//   which 2: Tq = Go + 5*Cq + lam*I   -> LTq  (+logdet)
//   which 3: Tk = Go + 5*Gk + lam*I   -> LTk  (+logdet)
// ---------------------------------------------------------------------------
__global__ __launch_bounds__(128) void chol4_kernel(
    const float* __restrict__ Gk, const float* __restrict__ Go, const float* __restrict__ Cq,
    float* __restrict__ Lk, float* __restrict__ Lo, float* __restrict__ LTq, float* __restrict__ LTk,
    float* __restrict__ ldbuf)
{
  __shared__ float A[128][128];
  const int bh = blockIdx.x, which = blockIdx.y, tid = threadIdx.x;
  const float* G1; const float* G2 = nullptr; float* Lout;
  if (which == 0)      { G1 = Gk; Lout = Lk;  }
  else if (which == 1) { G1 = Go; Lout = Lo;  }
  else if (which == 2) { G1 = Go; G2 = Cq; Lout = LTq; }
  else                 { G1 = Go; G2 = Gk; Lout = LTk; }
  const size_t base = (size_t)bh * 16384;
  for (int t = tid; t < 16384; t += 128) {
    float v = G1[base + t];
    if (G2) v = fmaf(5.f, G2[base + t], v);
    if ((t >> 7) == (t & 127)) v += 0.01f;
    A[t >> 7][t & 127] = v;
  }
  __syncthreads();
  const int j = tid;
  for (int k = 0; k < 128; ++k) {
    if (tid == 0) A[k][k] = sqrtf(A[k][k]);
    __syncthreads();
    const float dinv = 1.f / A[k][k];
    float cjk = 0.f;
    if (j > k) { cjk = A[j][k] * dinv; A[j][k] = cjk; }
    __syncthreads();
    for (int t = k + 1; t < 128; ++t) {
      if (j > k && j <= t) A[t][j] = fmaf(-cjk, A[t][k], A[t][j]);
    }
    __syncthreads();
  }
  const float lg = logf(A[tid][tid]);
  for (int t = tid; t < 16384; t += 128) {
    const int i = t >> 7, jj = t & 127;
    Lout[base + t] = (jj <= i) ? A[i][jj] : 0.f;
  }
  __syncthreads();
  A[0][tid] = lg;
  __syncthreads();
  if (tid == 0) {
    float s = 0.f;
    for (int i = 0; i < 128; ++i) s += A[0][i];
    ldbuf[which * 64 + bh] = 2.f * s;
  }
}

// ---------------------------------------------------------------------------
// 5 batched cho_solves per bh (thread = one RHS column):
//   which 0: Z1  = Ak^-1 PkTv   (64 rhs)
//   which 1: Aoi = Ao^-1 I      (128 rhs)
//   which 2: Z2  = Tq^-1 PhiTy  (64 rhs)
//   which 3: Wq2 = Tq^-1 Cq     (128 rhs)
//   which 4: Wk2 = Tk^-1 Gk     (128 rhs)
// ---------------------------------------------------------------------------
__global__ __launch_bounds__(128) void solve5_kernel(
    const float* __restrict__ Lk, const float* __restrict__ Lo,
    const float* __restrict__ LTq, const float* __restrict__ LTk,
    const float* __restrict__ PkTv, const float* __restrict__ PhiTy,
    const float* __restrict__ Cq, const float* __restrict__ Gk,
    float* __restrict__ Z1, float* __restrict__ Aoi,
    float* __restrict__ Z2, float* __restrict__ Wq2, float* __restrict__ Wk2)
{
  __shared__ float L[128][128];
  __shared__ float Xs[128][128];
  __shared__ float di[128];
  const int bh = blockIdx.x, which = blockIdx.y, tid = threadIdx.x;
  const float* Lsrc; const float* Bsrc; float* Out; int nr;
  if (which == 0)      { Lsrc = Lk;  Bsrc = PkTv;   Out = Z1;  nr = 64;  }
  else if (which == 1) { Lsrc = Lo;  Bsrc = nullptr; Out = Aoi; nr = 128; }
  else if (which == 2) { Lsrc = LTq; Bsrc = PhiTy;  Out = Z2;  nr = 64;  }
  else if (which == 3) { Lsrc = LTq; Bsrc = Cq;     Out = Wq2; nr = 128; }
  else                 { Lsrc = LTk; Bsrc = Gk;     Out = Wk2; nr = 128; }
  const int sh = (nr == 64) ? 6 : 7;
  const int mk = nr - 1;
  const size_t baseL = (size_t)bh * 16384;
  const size_t baseB = (size_t)bh * 128 * (size_t)nr;
  for (int t = tid; t < 16384; t += 128) L[t >> 7][t & 127] = Lsrc[baseL + t];
  if (Bsrc) {
    for (int t = tid; t < 128*nr; t += 128) Xs[t >> sh][t & mk] = Bsrc[baseB + t];
  } else {
    for (int t = tid; t < 16384; t += 128)
      Xs[t >> 7][t & 127] = ((t >> 7) == (t & 127)) ? 1.f : 0.f;
  }
  __syncthreads();
  di[tid] = 1.f / L[tid][tid];
  __syncthreads();
  const int c = tid;
  if (c < nr) {
    // forward: L y = b
    for (int i = 0; i < 128; ++i) {
      float s0 = 0.f, s1 = 0.f, s2 = 0.f, s3 = 0.f;
      int jj = 0;
      for (; jj + 3 < i; jj += 4) {
        s0 = fmaf(L[i][jj+0], Xs[jj+0][c], s0);
        s1 = fmaf(L[i][jj+1], Xs[jj+1][c], s1);
        s2 = fmaf(L[i][jj+2], Xs[jj+2][c], s2);
        s3 = fmaf(L[i][jj+3], Xs[jj+3][c], s3);
      }
      for (; jj < i; ++jj) s0 = fmaf(L[i][jj], Xs[jj][c], s0);
      const float s = Xs[i][c] - ((s0 + s1) + (s2 + s3));
      Xs[i][c] = s * di[i];
    }
    // backward: L^T x = y
    for (int i = 127; i >= 0; --i) {
      float s0 = 0.f, s1 = 0.f, s2 = 0.f, s3 = 0.f;
      int jj = i + 1;
      for (; jj + 3 < 128; jj += 4) {
        s0 = fmaf(L[jj+0][i], Xs[jj+0][c], s0);
        s1 = fmaf(L[jj+1][i], Xs[jj+1][c], s1);
        s2 = fmaf(L[jj+2][i], Xs[jj+2][c], s2);
        s3 = fmaf(L[jj+3][i], Xs[jj+3][c], s3);
      }
      for (; jj < 128; ++jj) s0 = fmaf(L[jj][i], Xs[jj][c], s0);
      const float s = Xs[i][c] - ((s0 + s1) + (s2 + s3));
      Xs[i][c] = s * di[i];
    }
  }
  __syncthreads();
  for (int t = tid; t < 128*nr; t += 128) Out[baseB + t] = Xs[t >> sh][t & mk];
}

// ---------------------------------------------------------------------------
// mid = Z1 - 0.01 * Aoi @ Z1   (128x128 @ 128x64), Aoi symmetric
// ---------------------------------------------------------------------------
__global__ __launch_bounds__(256) void mid_kernel(
    const float* __restrict__ Aoi, const float* __restrict__ Z1,
    float* __restrict__ midb)
{
  __shared__ alignas(16) float Ao[128][128];
  __shared__ alignas(16) float Z[128][64];
  const int bh = blockIdx.x, tid = threadIdx.x;
  const size_t bM = (size_t)bh * 16384, bD = (size_t)bh * 8192;
  for (int t4 = tid; t4 < 4096; t4 += 256) {
    const int r = t4 >> 5, c4 = (t4 & 31) << 2;
    *(float4*)&Ao[r][c4] = *(const float4*)(Aoi + bM + (size_t)r*128 + c4);
  }
  for (int t4 = tid; t4 < 2048; t4 += 256) {
    const int r = t4 >> 4, c4 = (t4 & 15) << 2;
    *(float4*)&Z[r][c4] = *(const float4*)(Z1 + bD + (size_t)r*64 + c4);
  }
  __syncthreads();
  const int ty = tid >> 4, tx = tid & 15;
  float acc[8][4];
#pragma unroll
  for (int i = 0; i < 8; ++i)
#pragma unroll
    for (int j = 0; j < 4; ++j) acc[i][j] = 0.f;
  for (int kk = 0; kk < 128; ++kk) {
    float4 a0 = *(const float4*)&Ao[kk][ty*8];     // Aoi symmetric: Ao[kk][r] = Aoi[r][kk]
    float4 a1 = *(const float4*)&Ao[kk][ty*8+4];
    float4 bv = *(const float4*)&Z[kk][tx*4];
    float a[8] = {a0.x, a0.y, a0.z, a0.w, a1.x, a1.y, a1.z, a1.w};
    float b[4] = {bv.x, bv.y, bv.z, bv.w};
#pragma unroll
    for (int i = 0; i < 8; ++i)
#pragma unroll
      for (int j = 0; j < 4; ++j) acc[i][j] = fmaf(a[i], b[j], acc[i][j]);
  }
#pragma unroll
  for (int i = 0; i < 8; ++i) {
    const int r = ty*8 + i, c = tx*4;
    float4 o;
    o.x = Z[r][c+0] - 0.01f*acc[i][0];
    o.y = Z[r][c+1] - 0.01f*acc[i][1];
    o.z = Z[r][c+2] - 0.01f*acc[i][2];
    o.w = Z[r][c+3] - 0.01f*acc[i][3];
    *(float4*)(midb + bD + (size_t)r*64 + c) = o;
  }
}

// ---------------------------------------------------------------------------
// Pq = Cq @ Wq2 ; Pk = Gk @ Wk2   (A operand symmetric)
// ---------------------------------------------------------------------------
__global__ __launch_bounds__(256) void pmat_kernel(
    const float* __restrict__ Cq, const float* __restrict__ Wq2,
    const float* __restrict__ Gk, const float* __restrict__ Wk2,
    float* __restrict__ Pq, float* __restrict__ Pk)
{
  __shared__ alignas(16) float Am[128][128];
  __shared__ alignas(16) float Bm[128][128];
  const int bh = blockIdx.x, which = blockIdx.y, tid = threadIdx.x;
  const float* Ap = which ? Gk : Cq;
  const float* Bp = which ? Wk2 : Wq2;
  float* Op = which ? Pk : Pq;
  const size_t base = (size_t)bh * 16384;
  for (int t4 = tid; t4 < 4096; t4 += 256) {
    const int r = t4 >> 5, c4 = (t4 & 31) << 2;
    *(float4*)&Am[r][c4] = *(const float4*)(Ap + base + (size_t)r*128 + c4);
    *(float4*)&Bm[r][c4] = *(const float4*)(Bp + base + (size_t)r*128 + c4);
  }
  __syncthreads();
  const int ty = tid >> 4, tx = tid & 15;
  float acc[8][8];
#pragma unroll
  for (int i = 0; i < 8; ++i)
#pragma unroll
    for (int j = 0; j < 8; ++j) acc[i][j] = 0.f;
  for (int kk = 0; kk < 128; ++kk) {
    float4 av0 = *(const float4*)&Am[kk][ty*8];    // A symmetric
    float4 av1 = *(const float4*)&Am[kk][ty*8+4];
    float4 bv0 = *(const float4*)&Bm[kk][tx*8];
    float4 bv1 = *(const float4*)&Bm[kk][tx*8+4];
    float a[8] = {av0.x, av0.y, av0.z, av0.w, av1.x, av1.y, av1.z, av1.w};
    float b[8] = {bv0.x, bv0.y, bv0.z, bv0.w, bv1.x, bv1.y, bv1.z, bv1.w};
#pragma unroll
    for (int i = 0; i < 8; ++i)
#pragma unroll
      for (int j = 0; j < 8; ++j) acc[i][j] = fmaf(a[i], b[j], acc[i][j]);
  }
#pragma unroll
  for (int i = 0; i < 8; ++i)
#pragma unroll
    for (int j = 0; j < 8; j += 4) {
      float4 o = {acc[i][j], acc[i][j+1], acc[i][j+2], acc[i][j+3]};
      *(float4*)(Op + base + (size_t)(ty*8+i)*128 + tx*8 + j) = o;
    }
}

// ---------------------------------------------------------------------------
// Per-bh scalar assembly of LB_q + LB_k.
// Uses: T = Ao + 5*C (SPD), S^-1 = T^-1/100, G_Ainv = I - 0.01*Aoi,
//       slogdet(I + 5 Aoi C) = logdet(T) - logdet(Ao).
// ---------------------------------------------------------------------------
__global__ __launch_bounds__(256) void scalars_kernel(
    const float* __restrict__ Aoi, const float* __restrict__ Cq, const float* __restrict__ Gk,
    const float* __restrict__ Pq, const float* __restrict__ Pk, const float* __restrict__ Wk2,
    const float* __restrict__ PhiTy, const float* __restrict__ Z2,
    const float* __restrict__ yyb, const float* __restrict__ ldb,
    float* __restrict__ regp)
{
  const int bh = blockIdx.x, tid = threadIdx.x;
  const size_t b0 = (size_t)bh * 16384, b1 = (size_t)bh * 8192;
  double aoCq=0, aoGk=0, aoPq=0, aoPk=0, wkGk=0, trCq=0, trGk=0, trPq=0, trPk=0, s1=0;
  for (int t = tid; t < 16384; t += 256) {
    const double ao = Aoi[b0+t], cq = Cq[b0+t], gk = Gk[b0+t];
    const double pq = Pq[b0+t], pk = Pk[b0+t], wk = Wk2[b0+t];
    aoCq += ao*cq; aoGk += ao*gk; aoPq += ao*pq; aoPk += ao*pk; wkGk += wk*gk;
    if (t % 129 == 0) { trCq += cq; trGk += gk; trPq += pq; trPk += pk; }
  }
  for (int t = tid; t < 8192; t += 256) s1 += (double)PhiTy[b1+t] * (double)Z2[b1+t];
  __shared__ double red[256];
  double vals[10] = {aoCq, aoGk, aoPq, aoPk, wkGk, trCq, trGk, trPq, trPk, s1};
  double tot[10];
  for (int vv = 0; vv < 10; ++vv) {
    red[tid] = vals[vv];
    __syncthreads();
    for (int st = 128; st > 0; st >>= 1) {
      if (tid < st) red[tid] += red[tid+st];
      __syncthreads();
    }
    tot[vv] = red[0];
    __syncthreads();
  }
  if (tid == 0) {
    const double D = 64.0, Nd = 2048.0;
    const double ldAo = ldb[64 + bh], ldTq = ldb[128 + bh], ldTk = ldb[192 + bh];
    const double yv = yyb[bh];
    const double cst  = Nd * log(2.0 * 3.14159265358979323846);
    const double leps = Nd * log(0.002);
    const double datq = 500.0*yv - 2500.0*tot[9];
    const double modq = D*(500.0*tot[5] - 2500.0*tot[7] - 0.01*(500.0*tot[0] - 2500.0*tot[2]));
    const double ldq  = leps + ldTq - ldAo;
    const double LBq  = -0.5*(datq + modq + ldq + cst);
    const double datk = D*(500.0*tot[6] - 2500.0*tot[4]);
    const double modk = D*(500.0*tot[6] - 2500.0*tot[8] - 0.01*(500.0*tot[1] - 2500.0*tot[3]));
    const double ldk  = leps + ldTk - ldAo;
    const double LBk  = -0.5*(datk + modk + ldk + cst);
    regp[bh] = (float)(-(LBq + LBk) / 64.0);
  }
}

__global__ void regfinal_kernel(const float* __restrict__ regp, float* __restrict__ outp)
{
  __shared__ float red[64];
  const int tid = threadIdx.x;
  red[tid] = regp[tid];
  __syncthreads();
  for (int st = 32; st > 0; st >>= 1) {
    if (tid < st) red[tid] += red[tid+st];
    __syncthreads();
  }
  if (tid == 0) outp[0] = red[0];
}

// ---------------------------------------------------------------------------
// y = Phi_q @ mid  -> written into (B,N,512) layout for final projection.
// Block = 128 rows of one (b,h).
// ---------------------------------------------------------------------------
__global__ __launch_bounds__(256) void y_kernel(
    const float* __restrict__ Phi, const float* __restrict__ midb,
    float* __restrict__ Yatt)
{
  __shared__ alignas(16) float Ps[128][128];
  __shared__ alignas(16) float Ms[128][64];
  const int blk = blockIdx.x;
  const int bh = blk >> 4, nt = blk & 15;
  const int b = bh >> 3, h = bh & 7;
  const int n0 = nt << 7;
  const int tid = threadIdx.x;
  for (int t4 = tid; t4 < 4096; t4 += 256) {
    const int r = t4 >> 5, c4 = (t4 & 31) << 2;
    *(float4*)&Ps[r][c4] = *(const float4*)(Phi + ((size_t)bh*N_ + n0 + r)*M_ + c4);
  }
  for (int t4 = tid; t4 < 2048; t4 += 256) {
    const int r = t4 >> 4, c4 = (t4 & 15) << 2;
    *(float4*)&Ms[r][c4] = *(const float4*)(midb + (size_t)bh*8192 + (size_t)r*64 + c4);
  }
  __syncthreads();
  const int ty = tid >> 4, tx = tid & 15;
  float acc[8][4];
#pragma unroll
  for (int i = 0; i < 8; ++i)
#pragma unroll
    for (int j = 0; j < 4; ++j) acc[i][j] = 0.f;
  for (int kk = 0; kk < 128; ++kk) {
    float4 bv = *(const float4*)&Ms[kk][tx*4];
    float b[4] = {bv.x, bv.y, bv.z, bv.w};
#pragma unroll
    for (int i = 0; i < 8; ++i) {
      const float a = Ps[ty*8+i][kk];
      acc[i][0] = fmaf(a, b[0], acc[i][0]);
      acc[i][1] = fmaf(a, b[1], acc[i][1]);
      acc[i][2] = fmaf(a, b[2], acc[i][2]);
      acc[i][3] = fmaf(a, b[3], acc[i][3]);
    }
  }
#pragma unroll
  for (int i = 0; i < 8; ++i) {
    float4 o = {acc[i][0], acc[i][1], acc[i][2], acc[i][3]};
    *(float4*)(Yatt + ((size_t)(b*N_) + n0 + ty*8 + i)*512 + h*64 + tx*4) = o;
  }
}

// ---------------------------------------------------------------------------
extern "C" void kernel_launch(void* const* d_in, const int* in_sizes, int n_in,
                              void* d_out, int out_size, void* d_ws, size_t ws_size,
                              hipStream_t stream)
{
  const float* x     = (const float*)d_in[0];
  const float* mask  = (const float*)d_in[1];
  const float* Wq    = (const float*)d_in[2];
  const float* bq    = (const float*)d_in[3];
  const float* Wk    = (const float*)d_in[4];
  const float* bk    = (const float*)d_in[5];
  const float* Wv    = (const float*)d_in[6];
  const float* bv    = (const float*)d_in[7];
  const float* Wx0   = (const float*)d_in[8];
  const float* bx0   = (const float*)d_in[9];
  const float* Wo    = (const float*)d_in[10];
  const float* bo    = (const float*)d_in[11];
  const float* omega = (const float*)d_in[12];
  const float* brff  = (const float*)d_in[13];
  float* outp = (float*)d_out;

  float* W_ = (float*)d_ws;
  size_t off = 0;
  auto take = [&](size_t n) -> float* { float* p = W_ + off; off += n; return p; };
  const size_t SZ_BNH = (size_t)8*2048*512;    // 8,388,608
  const size_t SZ_PHI = (size_t)64*2048*128;   // 16,777,216
  const size_t SZ_MM  = (size_t)64*128*128;    // 1,048,576
  const size_t SZ_MD  = (size_t)64*128*64;     //   524,288

  float* tmp  = take(SZ_BNH);   // holds x0, then k, then q heads
  float* vb   = take(SZ_BNH);
  float* Yat  = take(SZ_BNH);
  float* Phi  = take(SZ_PHI);   // holds Phi_o, then Phi_k, then Phi_q
  float* Gk   = take(SZ_MM);
  float* Go   = take(SZ_MM);
  float* Cq   = take(SZ_MM);
  float* Lk   = take(SZ_MM);
  float* Lo   = take(SZ_MM);
  float* LTq  = take(SZ_MM);
  float* LTk  = take(SZ_MM);
  float* Aoi  = take(SZ_MM);
  float* Wq2  = take(SZ_MM);
  float* Wk2  = take(SZ_MM);
  float* Pq   = take(SZ_MM);
  float* Pk   = take(SZ_MM);
  float* PkTv = take(SZ_MD);
  float* PhiTy= take(SZ_MD);
  float* Z1   = take(SZ_MD);
  float* Z2   = take(SZ_MD);
  float* midb = take(SZ_MD);
  float* Part = take(4*SZ_MM);
  float* yyb  = take(64);
  float* ldb  = take(256);
  float* regp = take(64);
  (void)ws_size; (void)in_sizes; (void)n_in; (void)out_size;

  // x0 path -> Go
  gemm_xwT<<<512, 256, 0, stream>>>(x, Wx0, bx0, nullptr, tmp);
  rff_kernel<<<32768, 128, 0, stream>>>(tmp, omega, brff, mask, Phi);
  gram_partial<<<dim3(64,4), 256, 0, stream>>>(Phi, Part);
  reduce4_kernel<<<4096, 256, 0, stream>>>(Part, Go, 1048576, (size_t)1048576);
  // k path -> Gk, PkTv
  gemm_xwT<<<512, 256, 0, stream>>>(x, Wk, bk, nullptr, tmp);
  rff_kernel<<<32768, 128, 0, stream>>>(tmp, omega, brff, mask, Phi);
  gram_partial<<<dim3(64,4), 256, 0, stream>>>(Phi, Part);
  reduce4_kernel<<<4096, 256, 0, stream>>>(Part, Gk, 1048576, (size_t)1048576);
  gemm_xwT<<<512, 256, 0, stream>>>(x, Wv, bv, mask, vb);
  phiTv_partial<<<dim3(64,4), 256, 0, stream>>>(Phi, vb, Part);
  reduce4_kernel<<<2048, 256, 0, stream>>>(Part, PkTv, 524288, (size_t)524288);
  // q path -> Cq, PhiTy (Phi now = Phi_q, stays live through y_kernel)
  gemm_xwT<<<512, 256, 0, stream>>>(x, Wq, bq, nullptr, tmp);
  rff_kernel<<<32768, 128, 0, stream>>>(tmp, omega, brff, mask, Phi);
  gram_partial<<<dim3(64,4), 256, 0, stream>>>(Phi, Part);
  reduce4_kernel<<<4096, 256, 0, stream>>>(Part, Cq, 1048576, (size_t)1048576);
  phiTv_partial<<<dim3(64,4), 256, 0, stream>>>(Phi, vb, Part);
  reduce4_kernel<<<2048, 256, 0, stream>>>(Part, PhiTy, 524288, (size_t)524288);
  yy_kernel<<<64, 256, 0, stream>>>(vb, yyb);
  // batched linear algebra
  chol4_kernel<<<dim3(64,4), 128, 0, stream>>>(Gk, Go, Cq, Lk, Lo, LTq, LTk, ldb);
  solve5_kernel<<<dim3(64,5), 128, 0, stream>>>(Lk, Lo, LTq, LTk, PkTv, PhiTy, Cq, Gk,
                                                Z1, Aoi, Z2, Wq2, Wk2);
  mid_kernel<<<64, 256, 0, stream>>>(Aoi, Z1, midb);
  pmat_kernel<<<dim3(64,2), 256, 0, stream>>>(Cq, Wq2, Gk, Wk2, Pq, Pk);
  scalars_kernel<<<64, 256, 0, stream>>>(Aoi, Cq, Gk, Pq, Pk, Wk2, PhiTy, Z2, yyb, ldb, regp);
  regfinal_kernel<<<1, 64, 0, stream>>>(regp, outp + SZ_BNH);
  // output path
  y_kernel<<<1024, 256, 0, stream>>>(Phi, midb, Yat);
  gemm_xwT<<<512, 256, 0, stream>>>(Yat, Wo, bo, nullptr, outp);
}

// Round 2
// 1600.415 us; speedup vs baseline: 1.5614x; 1.5614x over previous
//
#include <hip/hip_runtime.h>
#include <math.h>

// Problem constants
#define B_ 8
#define N_ 2048
#define HD_ 512
#define H_ 8
#define M_ 128
#define VD_ 64
// LAM = 0.01, EPS = 0.002 ; LAM/EPS = 5 ; 1/EPS = 500 ; 1/(100*EPS^2) = 2500

// ---------------------------------------------------------------------------
// GEMM: Y[r,c] = sum_k X[r,k]*W[c,k] + bias[c], optional per-row scale (mask).
// R=16384, K=512, C=512. 128x128 tile, 256 threads, 8x8 per thread.
// ---------------------------------------------------------------------------
__global__ __launch_bounds__(256) void gemm_xwT(
    const float* __restrict__ X, const float* __restrict__ Wm,
    const float* __restrict__ bias, const float* __restrict__ rowscale,
    float* __restrict__ Y)
{
  __shared__ alignas(16) float As[16][128];
  __shared__ alignas(16) float Bs[16][128];
  const int tid = threadIdx.x;
  const int bx = blockIdx.x & 3;
  const int by = blockIdx.x >> 2;
  const int row0 = by << 7, col0 = bx << 7;
  const int ty = tid >> 4, tx = tid & 15;
  float acc[8][8];
#pragma unroll
  for (int i = 0; i < 8; ++i)
#pragma unroll
    for (int j = 0; j < 8; ++j) acc[i][j] = 0.f;

  const int lr = tid >> 1;
  const int lk = (tid & 1) << 3;

  for (int k0 = 0; k0 < 512; k0 += 16) {
    float4 a0 = *(const float4*)(X + (size_t)(row0 + lr) * 512 + k0 + lk);
    float4 a1 = *(const float4*)(X + (size_t)(row0 + lr) * 512 + k0 + lk + 4);
    float4 b0 = *(const float4*)(Wm + (size_t)(col0 + lr) * 512 + k0 + lk);
    float4 b1 = *(const float4*)(Wm + (size_t)(col0 + lr) * 512 + k0 + lk + 4);
    As[lk+0][lr] = a0.x; As[lk+1][lr] = a0.y; As[lk+2][lr] = a0.z; As[lk+3][lr] = a0.w;
    As[lk+4][lr] = a1.x; As[lk+5][lr] = a1.y; As[lk+6][lr] = a1.z; As[lk+7][lr] = a1.w;
    Bs[lk+0][lr] = b0.x; Bs[lk+1][lr] = b0.y; Bs[lk+2][lr] = b0.z; Bs[lk+3][lr] = b0.w;
    Bs[lk+4][lr] = b1.x; Bs[lk+5][lr] = b1.y; Bs[lk+6][lr] = b1.z; Bs[lk+7][lr] = b1.w;
    __syncthreads();
#pragma unroll
    for (int kk = 0; kk < 16; ++kk) {
      float4 av0 = *(const float4*)&As[kk][ty*8];
      float4 av1 = *(const float4*)&As[kk][ty*8+4];
      float4 bv0 = *(const float4*)&Bs[kk][tx*8];
      float4 bv1 = *(const float4*)&Bs[kk][tx*8+4];
      float a[8] = {av0.x, av0.y, av0.z, av0.w, av1.x, av1.y, av1.z, av1.w};
      float b[8] = {bv0.x, bv0.y, bv0.z, bv0.w, bv1.x, bv1.y, bv1.z, bv1.w};
#pragma unroll
      for (int i = 0; i < 8; ++i)
#pragma unroll
        for (int j = 0; j < 8; ++j) acc[i][j] = fmaf(a[i], b[j], acc[i][j]);
    }
    __syncthreads();
  }
#pragma unroll
  for (int i = 0; i < 8; ++i) {
    const int r = row0 + ty*8 + i;
    const float rs = rowscale ? rowscale[r] : 1.f;
#pragma unroll
    for (int j = 0; j < 8; j += 4) {
      const int c = col0 + tx*8 + j;
      float4 o;
      o.x = (acc[i][j+0] + bias[c+0]) * rs;
      o.y = (acc[i][j+1] + bias[c+1]) * rs;
      o.z = (acc[i][j+2] + bias[c+2]) * rs;
      o.w = (acc[i][j+3] + bias[c+3]) * rs;
      *(float4*)(Y + (size_t)r * 512 + c) = o;
    }
  }
}

// ---------------------------------------------------------------------------
// RFF: Phi[bh,n,m] = 0.125 * cos( sum_d Q[b,n,h*64+d]*omega[d,m] + brff[m] ) * mask[b,n]
// ---------------------------------------------------------------------------
__global__ __launch_bounds__(128) void rff_kernel(
    const float* __restrict__ Q, const float* __restrict__ omega,
    const float* __restrict__ brff, const float* __restrict__ mask,
    float* __restrict__ Phi)
{
  const int m = threadIdx.x;
  const int blk = blockIdx.x;
  const int nc = blk & 511;   // N/4 = 512
  const int bh = blk >> 9;
  const int b = bh >> 3, h = bh & 7;
  const int n0 = nc << 2;
  __shared__ float qs[4][64];
  {
    const int r = m >> 6, d = m & 63;
    qs[r][d]   = Q[((size_t)(b*N_) + n0 + r) * 512 + h*64 + d];
    qs[r+2][d] = Q[((size_t)(b*N_) + n0 + r + 2) * 512 + h*64 + d];
  }
  __syncthreads();
  float z0 = 0.f, z1 = 0.f, z2 = 0.f, z3 = 0.f;
#pragma unroll 4
  for (int d = 0; d < 64; ++d) {
    const float om = omega[d*M_ + m];
    z0 = fmaf(qs[0][d], om, z0);
    z1 = fmaf(qs[1][d], om, z1);
    z2 = fmaf(qs[2][d], om, z2);
    z3 = fmaf(qs[3][d], om, z3);
  }
  const float bm = brff[m];
  const float sc = 0.125f;  // sqrt(2/128)
  const size_t ob = ((size_t)bh * N_ + n0) * M_ + m;
  const int mb = b*N_ + n0;
  Phi[ob      ] = sc * cosf(z0 + bm) * mask[mb+0];
  Phi[ob + 128] = sc * cosf(z1 + bm) * mask[mb+1];
  Phi[ob + 256] = sc * cosf(z2 + bm) * mask[mb+2];
  Phi[ob + 384] = sc * cosf(z3 + bm) * mask[mb+3];
}

// ---------------------------------------------------------------------------
// Gram partial
// ---------------------------------------------------------------------------
__global__ __launch_bounds__(256) void gram_partial(
    const float* __restrict__ Phi, float* __restrict__ Part)
{
  const int bh = blockIdx.x, sp = blockIdx.y, tid = threadIdx.x;
  __shared__ alignas(16) float Ps[16][128];
  const int ty = tid >> 4, tx = tid & 15;
  float acc[8][8];
#pragma unroll
  for (int i = 0; i < 8; ++i)
#pragma unroll
    for (int j = 0; j < 8; ++j) acc[i][j] = 0.f;
  const int lrow = tid >> 4, lcol = (tid & 15) << 3;
  for (int n0 = sp*512; n0 < sp*512 + 512; n0 += 16) {
    float4 p0 = *(const float4*)(Phi + ((size_t)bh*N_ + n0 + lrow)*M_ + lcol);
    float4 p1 = *(const float4*)(Phi + ((size_t)bh*N_ + n0 + lrow)*M_ + lcol + 4);
    *(float4*)&Ps[lrow][lcol]   = p0;
    *(float4*)&Ps[lrow][lcol+4] = p1;
    __syncthreads();
#pragma unroll
    for (int kk = 0; kk < 16; ++kk) {
      float4 av0 = *(const float4*)&Ps[kk][ty*8];
      float4 av1 = *(const float4*)&Ps[kk][ty*8+4];
      float4 bv0 = *(const float4*)&Ps[kk][tx*8];
      float4 bv1 = *(const float4*)&Ps[kk][tx*8+4];
      float a[8] = {av0.x, av0.y, av0.z, av0.w, av1.x, av1.y, av1.z, av1.w};
      float b[8] = {bv0.x, bv0.y, bv0.z, bv0.w, bv1.x, bv1.y, bv1.z, bv1.w};
#pragma unroll
      for (int i = 0; i < 8; ++i)
#pragma unroll
        for (int j = 0; j < 8; ++j) acc[i][j] = fmaf(a[i], b[j], acc[i][j]);
    }
    __syncthreads();
  }
  const size_t ob = ((size_t)sp*64 + bh) * 16384;
#pragma unroll
  for (int i = 0; i < 8; ++i)
#pragma unroll
    for (int j = 0; j < 8; j += 4) {
      float4 o = {acc[i][j], acc[i][j+1], acc[i][j+2], acc[i][j+3]};
      *(float4*)(Part + ob + (size_t)(ty*8+i)*128 + tx*8 + j) = o;
    }
}

// ---------------------------------------------------------------------------
// PhiT V partial
// ---------------------------------------------------------------------------
__global__ __launch_bounds__(256) void phiTv_partial(
    const float* __restrict__ Phi, const float* __restrict__ V,
    float* __restrict__ Part)
{
  const int bh = blockIdx.x, sp = blockIdx.y, tid = threadIdx.x;
  const int b = bh >> 3, h = bh & 7;
  __shared__ alignas(16) float Ps[16][128];
  __shared__ alignas(16) float Vs[16][64];
  const int ty = tid >> 3, tx = tid & 7;
  float acc[4][8];
#pragma unroll
  for (int i = 0; i < 4; ++i)
#pragma unroll
    for (int j = 0; j < 8; ++j) acc[i][j] = 0.f;
  const int lrow = tid >> 4, lcol = (tid & 15) << 3;
  const int vrow = tid >> 3, vcol = (tid & 7) << 3;
  for (int n0 = sp*512; n0 < sp*512 + 512; n0 += 16) {
    float4 p0 = *(const float4*)(Phi + ((size_t)bh*N_ + n0 + lrow)*M_ + lcol);
    float4 p1 = *(const float4*)(Phi + ((size_t)bh*N_ + n0 + lrow)*M_ + lcol + 4);
    *(float4*)&Ps[lrow][lcol]   = p0;
    *(float4*)&Ps[lrow][lcol+4] = p1;
    if (tid < 128) {
      float4 v0 = *(const float4*)(V + ((size_t)(b*N_) + n0 + vrow)*512 + h*64 + vcol);
      float4 v1 = *(const float4*)(V + ((size_t)(b*N_) + n0 + vrow)*512 + h*64 + vcol + 4);
      *(float4*)&Vs[vrow][vcol]   = v0;
      *(float4*)&Vs[vrow][vcol+4] = v1;
    }
    __syncthreads();
#pragma unroll
    for (int kk = 0; kk < 16; ++kk) {
      float4 av = *(const float4*)&Ps[kk][ty*4];
      float4 bv0 = *(const float4*)&Vs[kk][tx*8];
      float4 bv1 = *(const float4*)&Vs[kk][tx*8+4];
      float a[4] = {av.x, av.y, av.z, av.w};
      float b[8] = {bv0.x, bv0.y, bv0.z, bv0.w, bv1.x, bv1.y, bv1.z, bv1.w};
#pragma unroll
      for (int i = 0; i < 4; ++i)
#pragma unroll
        for (int j = 0; j < 8; ++j) acc[i][j] = fmaf(a[i], b[j], acc[i][j]);
    }
    __syncthreads();
  }
  const size_t ob = ((size_t)sp*64 + bh) * 8192;
#pragma unroll
  for (int i = 0; i < 4; ++i)
#pragma unroll
    for (int j = 0; j < 8; j += 4) {
      float4 o = {acc[i][j], acc[i][j+1], acc[i][j+2], acc[i][j+3]};
      *(float4*)(Part + ob + (size_t)(ty*4+i)*64 + tx*8 + j) = o;
    }
}

// ---------------------------------------------------------------------------
__global__ __launch_bounds__(256) void reduce4_kernel(
    const float* __restrict__ part, float* __restrict__ out, int n, size_t cs)
{
  const int i = blockIdx.x * 256 + threadIdx.x;
  if (i < n) out[i] = (part[i] + part[cs + i]) + (part[2*cs + i] + part[3*cs + i]);
}

// ---------------------------------------------------------------------------
__global__ __launch_bounds__(256) void yy_kernel(
    const float* __restrict__ V, float* __restrict__ yy)
{
  const int bh = blockIdx.x, tid = threadIdx.x;
  const int b = bh >> 3, h = bh & 7;
  float s = 0.f;
  for (int t = tid; t < N_*64; t += 256) {
    const int n = t >> 6, d = t & 63;
    const float v = V[((size_t)(b*N_) + n)*512 + h*64 + d];
    s = fmaf(v, v, s);
  }
  __shared__ float red[256];
  red[tid] = s; __syncthreads();
  for (int st = 128; st > 0; st >>= 1) {
    if (tid < st) red[tid] += red[tid+st];
    __syncthreads();
  }
  if (tid == 0) yy[bh] = red[0];
}

// ---------------------------------------------------------------------------
// Blocked batched Cholesky (NB=16), 256 threads, XOR-swizzled LDS.
//   which 0: Ak = Gk + lam*I          -> Lk
//   which 1: Ao = Go + lam*I          -> Lo   (+logdet)
//   which 2: Tq = Go + 5*Cq + lam*I   -> LTq  (+logdet)
//   which 3: Tk = Go + 5*Gk + lam*I   -> LTk  (+logdet)
// Output written SYMMETRICALLY: Lout[i][j] = L[i][j] (j<=i), = L[j][i] (j>i),
// so solve5 can read both L and L^T with contiguous uniform rows.
// ---------------------------------------------------------------------------
#define EL(i,j) As[(((i) << 7) | ((j) ^ ((i) & 31)))]

__global__ __launch_bounds__(256) void chol4_kernel(
    const float* __restrict__ Gk, const float* __restrict__ Go, const float* __restrict__ Cq,
    float* __restrict__ Lk, float* __restrict__ Lo, float* __restrict__ LTq, float* __restrict__ LTk,
    float* __restrict__ ldbuf)
{
  __shared__ float As[128*128];
  const int bh = blockIdx.x, which = blockIdx.y, tid = threadIdx.x;
  const float* G1; const float* G2 = nullptr; float* Lout;
  if (which == 0)      { G1 = Gk; Lout = Lk;  }
  else if (which == 1) { G1 = Go; Lout = Lo;  }
  else if (which == 2) { G1 = Go; G2 = Cq; Lout = LTq; }
  else                 { G1 = Go; G2 = Gk; Lout = LTk; }
  const size_t base = (size_t)bh * 16384;
  for (int t = tid; t < 16384; t += 256) {
    float v = G1[base + t];
    if (G2) v = fmaf(5.f, G2[base + t], v);
    const int i = t >> 7, j = t & 127;
    if (i == j) v += 0.01f;
    EL(i, j) = v;
  }
  __syncthreads();

  float ldacc = 0.f;
  for (int kb = 0; kb < 8; ++kb) {
    const int k0 = kb << 4;
    const int rbase = k0 + 16;
    const int R = 128 - rbase;
    // --- Phase A: every (needed) thread factors the 16x16 diag block in regs
    float Dg[16][16];
    float dinv[16];
    if (tid < 128) {
#pragma unroll
      for (int j = 0; j < 16; ++j)
#pragma unroll
        for (int p = 0; p < 16; ++p) if (p <= j) Dg[j][p] = EL(k0 + j, k0 + p);
#pragma unroll
      for (int kk = 0; kk < 16; ++kk) {
        const float d = sqrtf(Dg[kk][kk]);
        Dg[kk][kk] = d;
        const float di = 1.f / d;
        dinv[kk] = di;
#pragma unroll
        for (int r = 0; r < 16; ++r) if (r > kk) Dg[r][kk] *= di;
#pragma unroll
        for (int r = 0; r < 16; ++r) if (r > kk)
#pragma unroll
          for (int c2 = 0; c2 < 16; ++c2) if (c2 > kk && c2 <= r)
            Dg[r][c2] = fmaf(-Dg[r][kk], Dg[c2][kk], Dg[r][c2]);
      }
      if (tid == 0) {
#pragma unroll
        for (int kk = 0; kk < 16; ++kk) ldacc += logf(Dg[kk][kk]);
        // write factored diag block back (static indices, lane 0 only)
#pragma unroll
        for (int j = 0; j < 16; ++j)
#pragma unroll
          for (int p = 0; p < 16; ++p) if (p <= j) EL(k0 + j, k0 + p) = Dg[j][p];
      }
    }
    // --- Phase B: panel solve, one row per thread (rows rbase..127)
    if (tid < R) {
      const int r = rbase + tid;
      float xr[16];
#pragma unroll
      for (int p = 0; p < 16; ++p) xr[p] = EL(r, k0 + p);
#pragma unroll
      for (int j = 0; j < 16; ++j) {
        float s = xr[j];
#pragma unroll
        for (int p = 0; p < 16; ++p) if (p < j) s = fmaf(-Dg[j][p], xr[p], s);
        xr[j] = s * dinv[j];
      }
#pragma unroll
      for (int p = 0; p < 16; ++p) EL(r, k0 + p) = xr[p];
    }
    __syncthreads();
    // --- Phase C: trailing rank-16 update, 4x4 register tiles on lower triangle
    if (R > 0) {
      const int Rt = R >> 2;
      const int T = (Rt * (Rt + 1)) >> 1;
      for (int idx = tid; idx < T; idx += 256) {
        int ti = (int)((sqrtf(8.f * (float)idx + 1.f) - 1.f) * 0.5f);
        while (((ti + 1) * (ti + 2)) / 2 <= idx) ++ti;
        while ((ti * (ti + 1)) / 2 > idx) --ti;
        const int tj = idx - (ti * (ti + 1)) / 2;
        const int i0 = rbase + (ti << 2), j0 = rbase + (tj << 2);
        float Li[4][16], Lj[4][16], cc[4][4];
#pragma unroll
        for (int a = 0; a < 4; ++a)
#pragma unroll
          for (int p = 0; p < 16; ++p) Li[a][p] = EL(i0 + a, k0 + p);
#pragma unroll
        for (int bq2 = 0; bq2 < 4; ++bq2)
#pragma unroll
          for (int p = 0; p < 16; ++p) Lj[bq2][p] = EL(j0 + bq2, k0 + p);
#pragma unroll
        for (int a = 0; a < 4; ++a)
#pragma unroll
          for (int bq2 = 0; bq2 < 4; ++bq2) cc[a][bq2] = EL(i0 + a, j0 + bq2);
#pragma unroll
        for (int p = 0; p < 16; ++p)
#pragma unroll
          for (int a = 0; a < 4; ++a)
#pragma unroll
            for (int bq2 = 0; bq2 < 4; ++bq2)
              cc[a][bq2] = fmaf(-Li[a][p], Lj[bq2][p], cc[a][bq2]);
#pragma unroll
        for (int a = 0; a < 4; ++a)
#pragma unroll
          for (int bq2 = 0; bq2 < 4; ++bq2) EL(i0 + a, j0 + bq2) = cc[a][bq2];
      }
    }
    __syncthreads();
  }
  // write out symmetric L (upper = L^T) + logdet
  for (int t = tid; t < 16384; t += 256) {
    const int i = t >> 7, j = t & 127;
    Lout[base + t] = (j <= i) ? EL(i, j) : EL(j, i);
  }
  if (tid == 0) ldbuf[which * 64 + bh] = 2.f * ldacc;
}

// ---------------------------------------------------------------------------
// Blocked batched cho_solve (NB=16). One thread per RHS column.
// L is read from GLOBAL with block-uniform addresses (-> scalar s_loads);
// upper half of Lsrc holds L^T (written by chol4), so the backward pass also
// reads contiguous rows. X block cached in registers; eager panel updates.
//   which 0: Z1  = Ak^-1 PkTv   (64 rhs)
//   which 1: Aoi = Ao^-1 I      (128 rhs)
//   which 2: Z2  = Tq^-1 PhiTy  (64 rhs)
//   which 3: Wq2 = Tq^-1 Cq     (128 rhs)
//   which 4: Wk2 = Tk^-1 Gk     (128 rhs)
// ---------------------------------------------------------------------------
__global__ __launch_bounds__(128) void solve5_kernel(
    const float* __restrict__ Lk, const float* __restrict__ Lo,
    const float* __restrict__ LTq, const float* __restrict__ LTk,
    const float* __restrict__ PkTv, const float* __restrict__ PhiTy,
    const float* __restrict__ Cq, const float* __restrict__ Gk,
    float* __restrict__ Z1, float* __restrict__ Aoi,
    float* __restrict__ Z2, float* __restrict__ Wq2, float* __restrict__ Wk2)
{
  __shared__ float Xs[128][128];
  const int bh = blockIdx.x, which = blockIdx.y, tid = threadIdx.x;
  const float* Lsrc; const float* Bsrc; float* Out; int nr;
  if (which == 0)      { Lsrc = Lk;  Bsrc = PkTv;    Out = Z1;  nr = 64;  }
  else if (which == 1) { Lsrc = Lo;  Bsrc = nullptr; Out = Aoi; nr = 128; }
  else if (which == 2) { Lsrc = LTq; Bsrc = PhiTy;   Out = Z2;  nr = 64;  }
  else if (which == 3) { Lsrc = LTq; Bsrc = Cq;      Out = Wq2; nr = 128; }
  else                 { Lsrc = LTk; Bsrc = Gk;      Out = Wk2; nr = 128; }
  const int sh = (nr == 64) ? 6 : 7;
  const int mk = nr - 1;
  const size_t baseL = (size_t)bh * 16384;
  const size_t baseB = (size_t)bh * 128 * (size_t)nr;
  if (Bsrc) {
    for (int t = tid; t < 128 * nr; t += 128) Xs[t >> sh][t & mk] = Bsrc[baseB + t];
  } else {
    for (int t = tid; t < 16384; t += 128)
      Xs[t >> 7][t & 127] = ((t >> 7) == (t & 127)) ? 1.f : 0.f;
  }
  __syncthreads();
  const int c = tid;
  if (c < nr) {
    float xb[16];
    // ---- forward: L y = b (blocked, eager updates) ----
    for (int kb = 0; kb < 8; ++kb) {
      const int k0 = kb << 4;
#pragma unroll
      for (int p = 0; p < 16; ++p) xb[p] = Xs[k0 + p][c];
#pragma unroll
      for (int j = 0; j < 16; ++j) {
        const float* Lr = Lsrc + baseL + (size_t)(k0 + j) * 128 + k0;
        float s = xb[j];
#pragma unroll
        for (int p = 0; p < 16; ++p) if (p < j) s = fmaf(-Lr[p], xb[p], s);
        xb[j] = s / Lr[j];
      }
#pragma unroll
      for (int p = 0; p < 16; ++p) Xs[k0 + p][c] = xb[p];
      for (int r = k0 + 16; r < 128; ++r) {
        const float* Lr = Lsrc + baseL + (size_t)r * 128 + k0;
        float s = Xs[r][c];
#pragma unroll
        for (int p = 0; p < 16; ++p) s = fmaf(-Lr[p], xb[p], s);
        Xs[r][c] = s;
      }
    }
    // ---- backward: L^T x = y (upper half of Lsrc = L^T) ----
    for (int kb = 7; kb >= 0; --kb) {
      const int k0 = kb << 4;
#pragma unroll
      for (int p = 0; p < 16; ++p) xb[p] = Xs[k0 + p][c];
#pragma unroll
      for (int j = 15; j >= 0; --j) {
        const float* Lr = Lsrc + baseL + (size_t)(k0 + j) * 128 + k0; // row k0+j: cols>j hold L^T
        float s = xb[j];
#pragma unroll
        for (int p = 0; p < 16; ++p) if (p > j) s = fmaf(-Lr[p], xb[p], s);
        xb[j] = s / Lr[j];
      }
#pragma unroll
      for (int p = 0; p < 16; ++p) Xs[k0 + p][c] = xb[p];
      for (int r = 0; r < k0; ++r) {
        const float* Lr = Lsrc + baseL + (size_t)r * 128 + k0; // upper: L^T[r][k0+p]
        float s = Xs[r][c];
#pragma unroll
        for (int p = 0; p < 16; ++p) s = fmaf(-Lr[p], xb[p], s);
        Xs[r][c] = s;
      }
    }
  }
  __syncthreads();
  for (int t = tid; t < 128 * nr; t += 128) Out[baseB + t] = Xs[t >> sh][t & mk];
}

// ---------------------------------------------------------------------------
// mid = Z1 - 0.01 * Aoi @ Z1   (Aoi symmetric)
// ---------------------------------------------------------------------------
__global__ __launch_bounds__(256) void mid_kernel(
    const float* __restrict__ Aoi, const float* __restrict__ Z1,
    float* __restrict__ midb)
{
  __shared__ alignas(16) float Ao[128][128];
  __shared__ alignas(16) float Z[128][64];
  const int bh = blockIdx.x, tid = threadIdx.x;
  const size_t bM = (size_t)bh * 16384, bD = (size_t)bh * 8192;
  for (int t4 = tid; t4 < 4096; t4 += 256) {
    const int r = t4 >> 5, c4 = (t4 & 31) << 2;
    *(float4*)&Ao[r][c4] = *(const float4*)(Aoi + bM + (size_t)r*128 + c4);
  }
  for (int t4 = tid; t4 < 2048; t4 += 256) {
    const int r = t4 >> 4, c4 = (t4 & 15) << 2;
    *(float4*)&Z[r][c4] = *(const float4*)(Z1 + bD + (size_t)r*64 + c4);
  }
  __syncthreads();
  const int ty = tid >> 4, tx = tid & 15;
  float acc[8][4];
#pragma unroll
  for (int i = 0; i < 8; ++i)
#pragma unroll
    for (int j = 0; j < 4; ++j) acc[i][j] = 0.f;
  for (int kk = 0; kk < 128; ++kk) {
    float4 a0 = *(const float4*)&Ao[kk][ty*8];
    float4 a1 = *(const float4*)&Ao[kk][ty*8+4];
    float4 bv = *(const float4*)&Z[kk][tx*4];
    float a[8] = {a0.x, a0.y, a0.z, a0.w, a1.x, a1.y, a1.z, a1.w};
    float b[4] = {bv.x, bv.y, bv.z, bv.w};
#pragma unroll
    for (int i = 0; i < 8; ++i)
#pragma unroll
      for (int j = 0; j < 4; ++j) acc[i][j] = fmaf(a[i], b[j], acc[i][j]);
  }
#pragma unroll
  for (int i = 0; i < 8; ++i) {
    const int r = ty*8 + i, c = tx*4;
    float4 o;
    o.x = Z[r][c+0] - 0.01f*acc[i][0];
    o.y = Z[r][c+1] - 0.01f*acc[i][1];
    o.z = Z[r][c+2] - 0.01f*acc[i][2];
    o.w = Z[r][c+3] - 0.01f*acc[i][3];
    *(float4*)(midb + bD + (size_t)r*64 + c) = o;
  }
}

// ---------------------------------------------------------------------------
// Pq = Cq @ Wq2 ; Pk = Gk @ Wk2   (A operand symmetric)
// ---------------------------------------------------------------------------
__global__ __launch_bounds__(256) void pmat_kernel(
    const float* __restrict__ Cq, const float* __restrict__ Wq2,
    const float* __restrict__ Gk, const float* __restrict__ Wk2,
    float* __restrict__ Pq, float* __restrict__ Pk)
{
  __shared__ alignas(16) float Am[128][128];
  __shared__ alignas(16) float Bm[128][128];
  const int bh = blockIdx.x, which = blockIdx.y, tid = threadIdx.x;
  const float* Ap = which ? Gk : Cq;
  const float* Bp = which ? Wk2 : Wq2;
  float* Op = which ? Pk : Pq;
  const size_t base = (size_t)bh * 16384;
  for (int t4 = tid; t4 < 4096; t4 += 256) {
    const int r = t4 >> 5, c4 = (t4 & 31) << 2;
    *(float4*)&Am[r][c4] = *(const float4*)(Ap + base + (size_t)r*128 + c4);
    *(float4*)&Bm[r][c4] = *(const float4*)(Bp + base + (size_t)r*128 + c4);
  }
  __syncthreads();
  const int ty = tid >> 4, tx = tid & 15;
  float acc[8][8];
#pragma unroll
  for (int i = 0; i < 8; ++i)
#pragma unroll
    for (int j = 0; j < 8; ++j) acc[i][j] = 0.f;
  for (int kk = 0; kk < 128; ++kk) {
    float4 av0 = *(const float4*)&Am[kk][ty*8];
    float4 av1 = *(const float4*)&Am[kk][ty*8+4];
    float4 bv0 = *(const float4*)&Bm[kk][tx*8];
    float4 bv1 = *(const float4*)&Bm[kk][tx*8+4];
    float a[8] = {av0.x, av0.y, av0.z, av0.w, av1.x, av1.y, av1.z, av1.w};
    float b[8] = {bv0.x, bv0.y, bv0.z, bv0.w, bv1.x, bv1.y, bv1.z, bv1.w};
#pragma unroll
    for (int i = 0; i < 8; ++i)
#pragma unroll
      for (int j = 0; j < 8; ++j) acc[i][j] = fmaf(a[i], b[j], acc[i][j]);
  }
#pragma unroll
  for (int i = 0; i < 8; ++i)
#pragma unroll
    for (int j = 0; j < 8; j += 4) {
      float4 o = {acc[i][j], acc[i][j+1], acc[i][j+2], acc[i][j+3]};
      *(float4*)(Op + base + (size_t)(ty*8+i)*128 + tx*8 + j) = o;
    }
}

// ---------------------------------------------------------------------------
__global__ __launch_bounds__(256) void scalars_kernel(
    const float* __restrict__ Aoi, const float* __restrict__ Cq, const float* __restrict__ Gk,
    const float* __restrict__ Pq, const float* __restrict__ Pk, const float* __restrict__ Wk2,
    const float* __restrict__ PhiTy, const float* __restrict__ Z2,
    const float* __restrict__ yyb, const float* __restrict__ ldb,
    float* __restrict__ regp)
{
  const int bh = blockIdx.x, tid = threadIdx.x;
  const size_t b0 = (size_t)bh * 16384, b1 = (size_t)bh * 8192;
  double aoCq=0, aoGk=0, aoPq=0, aoPk=0, wkGk=0, trCq=0, trGk=0, trPq=0, trPk=0, s1=0;
  for (int t = tid; t < 16384; t += 256) {
    const double ao = Aoi[b0+t], cq = Cq[b0+t], gk = Gk[b0+t];
    const double pq = Pq[b0+t], pk = Pk[b0+t], wk = Wk2[b0+t];
    aoCq += ao*cq; aoGk += ao*gk; aoPq += ao*pq; aoPk += ao*pk; wkGk += wk*gk;
    if (t % 129 == 0) { trCq += cq; trGk += gk; trPq += pq; trPk += pk; }
  }
  for (int t = tid; t < 8192; t += 256) s1 += (double)PhiTy[b1+t] * (double)Z2[b1+t];
  __shared__ double red[256];
  double vals[10] = {aoCq, aoGk, aoPq, aoPk, wkGk, trCq, trGk, trPq, trPk, s1};
  double tot[10];
  for (int vv = 0; vv < 10; ++vv) {
    red[tid] = vals[vv];
    __syncthreads();
    for (int st = 128; st > 0; st >>= 1) {
      if (tid < st) red[tid] += red[tid+st];
      __syncthreads();
    }
    tot[vv] = red[0];
    __syncthreads();
  }
  if (tid == 0) {
    const double D = 64.0, Nd = 2048.0;
    const double ldAo = ldb[64 + bh], ldTq = ldb[128 + bh], ldTk = ldb[192 + bh];
    const double yv = yyb[bh];
    const double cst  = Nd * log(2.0 * 3.14159265358979323846);
    const double leps = Nd * log(0.002);
    const double datq = 500.0*yv - 2500.0*tot[9];
    const double modq = D*(500.0*tot[5] - 2500.0*tot[7] - 0.01*(500.0*tot[0] - 2500.0*tot[2]));
    const double ldq  = leps + ldTq - ldAo;
    const double LBq  = -0.5*(datq + modq + ldq + cst);
    const double datk = D*(500.0*tot[6] - 2500.0*tot[4]);
    const double modk = D*(500.0*tot[6] - 2500.0*tot[8] - 0.01*(500.0*tot[1] - 2500.0*tot[3]));
    const double ldk  = leps + ldTk - ldAo;
    const double LBk  = -0.5*(datk + modk + ldk + cst);
    regp[bh] = (float)(-(LBq + LBk) / 64.0);
  }
}

__global__ void regfinal_kernel(const float* __restrict__ regp, float* __restrict__ outp)
{
  __shared__ float red[64];
  const int tid = threadIdx.x;
  red[tid] = regp[tid];
  __syncthreads();
  for (int st = 32; st > 0; st >>= 1) {
    if (tid < st) red[tid] += red[tid+st];
    __syncthreads();
  }
  if (tid == 0) outp[0] = red[0];
}

// ---------------------------------------------------------------------------
// y = Phi_q @ mid
// ---------------------------------------------------------------------------
__global__ __launch_bounds__(256) void y_kernel(
    const float* __restrict__ Phi, const float* __restrict__ midb,
    float* __restrict__ Yatt)
{
  __shared__ alignas(16) float Ps[128][128];
  __shared__ alignas(16) float Ms[128][64];
  const int blk = blockIdx.x;
  const int bh = blk >> 4, nt = blk & 15;
  const int b = bh >> 3, h = bh & 7;
  const int n0 = nt << 7;
  const int tid = threadIdx.x;
  for (int t4 = tid; t4 < 4096; t4 += 256) {
    const int r = t4 >> 5, c4 = (t4 & 31) << 2;
    *(float4*)&Ps[r][c4] = *(const float4*)(Phi + ((size_t)bh*N_ + n0 + r)*M_ + c4);
  }
  for (int t4 = tid; t4 < 2048; t4 += 256) {
    const int r = t4 >> 4, c4 = (t4 & 15) << 2;
    *(float4*)&Ms[r][c4] = *(const float4*)(midb + (size_t)bh*8192 + (size_t)r*64 + c4);
  }
  __syncthreads();
  const int ty = tid >> 4, tx = tid & 15;
  float acc[8][4];
#pragma unroll
  for (int i = 0; i < 8; ++i)
#pragma unroll
    for (int j = 0; j < 4; ++j) acc[i][j] = 0.f;
  for (int kk = 0; kk < 128; ++kk) {
    float4 bv = *(const float4*)&Ms[kk][tx*4];
    float b[4] = {bv.x, bv.y, bv.z, bv.w};
#pragma unroll
    for (int i = 0; i < 8; ++i) {
      const float a = Ps[ty*8+i][kk];
      acc[i][0] = fmaf(a, b[0], acc[i][0]);
      acc[i][1] = fmaf(a, b[1], acc[i][1]);
      acc[i][2] = fmaf(a, b[2], acc[i][2]);
      acc[i][3] = fmaf(a, b[3], acc[i][3]);
    }
  }
#pragma unroll
  for (int i = 0; i < 8; ++i) {
    float4 o = {acc[i][0], acc[i][1], acc[i][2], acc[i][3]};
    *(float4*)(Yatt + ((size_t)(b*N_) + n0 + ty*8 + i)*512 + h*64 + tx*4) = o;
  }
}

// ---------------------------------------------------------------------------
extern "C" void kernel_launch(void* const* d_in, const int* in_sizes, int n_in,
                              void* d_out, int out_size, void* d_ws, size_t ws_size,
                              hipStream_t stream)
{
  const float* x     = (const float*)d_in[0];
  const float* mask  = (const float*)d_in[1];
  const float* Wq    = (const float*)d_in[2];
  const float* bq    = (const float*)d_in[3];
  const float* Wk    = (const float*)d_in[4];
  const float* bk    = (const float*)d_in[5];
  const float* Wv    = (const float*)d_in[6];
  const float* bv    = (const float*)d_in[7];
  const float* Wx0   = (const float*)d_in[8];
  const float* bx0   = (const float*)d_in[9];
  const float* Wo    = (const float*)d_in[10];
  const float* bo    = (const float*)d_in[11];
  const float* omega = (const float*)d_in[12];
  const float* brff  = (const float*)d_in[13];
  float* outp = (float*)d_out;

  float* W_ = (float*)d_ws;
  size_t off = 0;
  auto take = [&](size_t n) -> float* { float* p = W_ + off; off += n; return p; };
  const size_t SZ_BNH = (size_t)8*2048*512;
  const size_t SZ_PHI = (size_t)64*2048*128;
  const size_t SZ_MM  = (size_t)64*128*128;
  const size_t SZ_MD  = (size_t)64*128*64;

  float* tmp  = take(SZ_BNH);
  float* vb   = take(SZ_BNH);
  float* Yat  = take(SZ_BNH);
  float* Phi  = take(SZ_PHI);
  float* Gk   = take(SZ_MM);
  float* Go   = take(SZ_MM);
  float* Cq   = take(SZ_MM);
  float* Lk   = take(SZ_MM);
  float* Lo   = take(SZ_MM);
  float* LTq  = take(SZ_MM);
  float* LTk  = take(SZ_MM);
  float* Aoi  = take(SZ_MM);
  float* Wq2  = take(SZ_MM);
  float* Wk2  = take(SZ_MM);
  float* Pq   = take(SZ_MM);
  float* Pk   = take(SZ_MM);
  float* PkTv = take(SZ_MD);
  float* PhiTy= take(SZ_MD);
  float* Z1   = take(SZ_MD);
  float* Z2   = take(SZ_MD);
  float* midb = take(SZ_MD);
  float* Part = take(4*SZ_MM);
  float* yyb  = take(64);
  float* ldb  = take(256);
  float* regp = take(64);
  (void)ws_size; (void)in_sizes; (void)n_in; (void)out_size;

  // x0 path -> Go
  gemm_xwT<<<512, 256, 0, stream>>>(x, Wx0, bx0, nullptr, tmp);
  rff_kernel<<<32768, 128, 0, stream>>>(tmp, omega, brff, mask, Phi);
  gram_partial<<<dim3(64,4), 256, 0, stream>>>(Phi, Part);
  reduce4_kernel<<<4096, 256, 0, stream>>>(Part, Go, 1048576, (size_t)1048576);
  // k path -> Gk, PkTv
  gemm_xwT<<<512, 256, 0, stream>>>(x, Wk, bk, nullptr, tmp);
  rff_kernel<<<32768, 128, 0, stream>>>(tmp, omega, brff, mask, Phi);
  gram_partial<<<dim3(64,4), 256, 0, stream>>>(Phi, Part);
  reduce4_kernel<<<4096, 256, 0, stream>>>(Part, Gk, 1048576, (size_t)1048576);
  gemm_xwT<<<512, 256, 0, stream>>>(x, Wv, bv, mask, vb);
  phiTv_partial<<<dim3(64,4), 256, 0, stream>>>(Phi, vb, Part);
  reduce4_kernel<<<2048, 256, 0, stream>>>(Part, PkTv, 524288, (size_t)524288);
  // q path -> Cq, PhiTy
  gemm_xwT<<<512, 256, 0, stream>>>(x, Wq, bq, nullptr, tmp);
  rff_kernel<<<32768, 128, 0, stream>>>(tmp, omega, brff, mask, Phi);
  gram_partial<<<dim3(64,4), 256, 0, stream>>>(Phi, Part);
  reduce4_kernel<<<4096, 256, 0, stream>>>(Part, Cq, 1048576, (size_t)1048576);
  phiTv_partial<<<dim3(64,4), 256, 0, stream>>>(Phi, vb, Part);
  reduce4_kernel<<<2048, 256, 0, stream>>>(Part, PhiTy, 524288, (size_t)524288);
  yy_kernel<<<64, 256, 0, stream>>>(vb, yyb);
  // batched linear algebra
  chol4_kernel<<<dim3(64,4), 256, 0, stream>>>(Gk, Go, Cq, Lk, Lo, LTq, LTk, ldb);
  solve5_kernel<<<dim3(64,5), 128, 0, stream>>>(Lk, Lo, LTq, LTk, PkTv, PhiTy, Cq, Gk,
                                                Z1, Aoi, Z2, Wq2, Wk2);
  mid_kernel<<<64, 256, 0, stream>>>(Aoi, Z1, midb);
  pmat_kernel<<<dim3(64,2), 256, 0, stream>>>(Cq, Wq2, Gk, Wk2, Pq, Pk);
  scalars_kernel<<<64, 256, 0, stream>>>(Aoi, Cq, Gk, Pq, Pk, Wk2, PhiTy, Z2, yyb, ldb, regp);
  regfinal_kernel<<<1, 64, 0, stream>>>(regp, outp + SZ_BNH);
  // output path
  y_kernel<<<1024, 256, 0, stream>>>(Phi, midb, Yat);
  gemm_xwT<<<512, 256, 0, stream>>>(Yat, Wo, bo, nullptr, outp);
}

// Round 3
// 1101.963 us; speedup vs baseline: 2.2677x; 1.4523x over previous
//
#include <hip/hip_runtime.h>
#include <math.h>

// Problem constants
#define B_ 8
#define N_ 2048
#define HD_ 512
#define H_ 8
#define M_ 128
#define VD_ 64
// LAM = 0.01, EPS = 0.002 ; LAM/EPS = 5 ; 1/EPS = 500 ; 1/(100*EPS^2) = 2500

typedef __attribute__((ext_vector_type(8))) short short8v;   // 8 bf16 (4 VGPRs)
typedef __attribute__((ext_vector_type(4))) float f32x4;

__device__ __forceinline__ unsigned short f2bf(float f) {
  unsigned u = __float_as_uint(f);
  u += 0x7FFF + ((u >> 16) & 1);   // round-to-nearest-even
  return (unsigned short)(u >> 16);
}
__device__ __forceinline__ float bf2f(unsigned short h) {
  return __uint_as_float(((unsigned)h) << 16);
}

// ---------------------------------------------------------------------------
// Split fp32 -> (hi, lo) bf16 pair: hi = bf16(a), lo = bf16(a - hi).
// ---------------------------------------------------------------------------
__global__ __launch_bounds__(256) void split_kernel(
    const float* __restrict__ in, unsigned short* __restrict__ hi,
    unsigned short* __restrict__ lo, int n)
{
  const int i = (blockIdx.x * 256 + threadIdx.x) << 2;
  if (i >= n) return;
  float4 v = *(const float4*)(in + i);
  ushort4 h, l;
  h.x = f2bf(v.x); l.x = f2bf(v.x - bf2f(h.x));
  h.y = f2bf(v.y); l.y = f2bf(v.y - bf2f(h.y));
  h.z = f2bf(v.z); l.z = f2bf(v.z - bf2f(h.z));
  h.w = f2bf(v.w); l.w = f2bf(v.w - bf2f(h.w));
  *(ushort4*)(hi + i) = h;
  *(ushort4*)(lo + i) = l;
}

// ---------------------------------------------------------------------------
// bf16x3 MFMA GEMM: Y[r,c] = sum_k A[r,k]*B[c,k] + bias[c], optional rowscale.
// A = Ahi+Alo, B = Bhi+Blo; acc = Ahi*Bhi + Ahi*Blo + Alo*Bhi (err ~2^-16).
// M=16384, N=512, K=512. 128x128 tile, 256 thr = 4 waves, each wave 64x64
// (4x4 frags of mfma_f32_16x16x32_bf16). LDS rows padded to 40 ushorts.
// ---------------------------------------------------------------------------
#define LDP 40
__global__ __launch_bounds__(256) void gemm_mfma(
    const unsigned short* __restrict__ Ahi, const unsigned short* __restrict__ Alo,
    const unsigned short* __restrict__ Bhi, const unsigned short* __restrict__ Blo,
    const float* __restrict__ bias, const float* __restrict__ rowscale,
    float* __restrict__ Y)
{
  __shared__ unsigned short Ah[128 * LDP], Al[128 * LDP];
  __shared__ unsigned short Bh[128 * LDP], Bl[128 * LDP];
  const int tid = threadIdx.x;
  const int bx = blockIdx.x & 3, by = blockIdx.x >> 2;
  const int row0 = by << 7, col0 = bx << 7;
  const int lane = tid & 63, wave = tid >> 6;
  const int wr = wave >> 1, wc = wave & 1;
  const int fr = lane & 15, fk = (lane >> 4) << 3;
  f32x4 acc[4][4];
#pragma unroll
  for (int i = 0; i < 4; ++i)
#pragma unroll
    for (int j = 0; j < 4; ++j) acc[i][j] = (f32x4){0.f, 0.f, 0.f, 0.f};

  const int srow = tid >> 2;          // 0..63
  const int sch = (tid & 3) << 3;     // 0,8,16,24
  const size_t ga = (size_t)(row0 + srow) * 512 + sch;
  const size_t gb = (size_t)(col0 + srow) * 512 + sch;

  short8v rah0, rah1, ral0, ral1, rbh0, rbh1, rbl0, rbl1;
#define LOADREGS(k)                                                          \
  rah0 = *(const short8v*)(Ahi + ga + (k));                                  \
  rah1 = *(const short8v*)(Ahi + ga + (size_t)64 * 512 + (k));               \
  ral0 = *(const short8v*)(Alo + ga + (k));                                  \
  ral1 = *(const short8v*)(Alo + ga + (size_t)64 * 512 + (k));               \
  rbh0 = *(const short8v*)(Bhi + gb + (k));                                  \
  rbh1 = *(const short8v*)(Bhi + gb + (size_t)64 * 512 + (k));               \
  rbl0 = *(const short8v*)(Blo + gb + (k));                                  \
  rbl1 = *(const short8v*)(Blo + gb + (size_t)64 * 512 + (k));

  LOADREGS(0)
  for (int kt = 0; kt < 16; ++kt) {
    __syncthreads();   // previous tile's compute done
    *(short8v*)&Ah[srow * LDP + sch] = rah0;
    *(short8v*)&Ah[(srow + 64) * LDP + sch] = rah1;
    *(short8v*)&Al[srow * LDP + sch] = ral0;
    *(short8v*)&Al[(srow + 64) * LDP + sch] = ral1;
    *(short8v*)&Bh[srow * LDP + sch] = rbh0;
    *(short8v*)&Bh[(srow + 64) * LDP + sch] = rbh1;
    *(short8v*)&Bl[srow * LDP + sch] = rbl0;
    *(short8v*)&Bl[(srow + 64) * LDP + sch] = rbl1;
    __syncthreads();
    if (kt < 15) { LOADREGS((kt + 1) * 32) }   // prefetch overlaps MFMA
    short8v a_hi[4], a_lo[4];
#pragma unroll
    for (int i = 0; i < 4; ++i) {
      const int ar = (wr * 64 + i * 16 + fr) * LDP + fk;
      a_hi[i] = *(const short8v*)&Ah[ar];
      a_lo[i] = *(const short8v*)&Al[ar];
    }
#pragma unroll
    for (int j = 0; j < 4; ++j) {
      const int br = (wc * 64 + j * 16 + fr) * LDP + fk;
      short8v b_hi = *(const short8v*)&Bh[br];
      short8v b_lo = *(const short8v*)&Bl[br];
#pragma unroll
      for (int i = 0; i < 4; ++i) {
        acc[i][j] = __builtin_amdgcn_mfma_f32_16x16x32_bf16(a_hi[i], b_hi, acc[i][j], 0, 0, 0);
        acc[i][j] = __builtin_amdgcn_mfma_f32_16x16x32_bf16(a_hi[i], b_lo, acc[i][j], 0, 0, 0);
        acc[i][j] = __builtin_amdgcn_mfma_f32_16x16x32_bf16(a_lo[i], b_hi, acc[i][j], 0, 0, 0);
      }
    }
  }
  // epilogue: C/D layout col = lane&15, row = (lane>>4)*4 + reg
  const int rbase = row0 + wr * 64 + ((lane >> 4) << 2);
#pragma unroll
  for (int j = 0; j < 4; ++j) {
    const int col = col0 + wc * 64 + j * 16 + fr;
    const float bc = bias[col];
#pragma unroll
    for (int i = 0; i < 4; ++i) {
      const int r0 = rbase + i * 16;
#pragma unroll
      for (int r = 0; r < 4; ++r) {
        float v = acc[i][j][r] + bc;
        if (rowscale) v *= rowscale[r0 + r];
        Y[(size_t)(r0 + r) * 512 + col] = v;
      }
    }
  }
}
#undef LOADREGS

// ---------------------------------------------------------------------------
// RFF: Phi[bh,n,m] = 0.125 * cos( sum_d Q[b,n,h*64+d]*omega[d,m] + brff[m] ) * mask[b,n]
// ---------------------------------------------------------------------------
__global__ __launch_bounds__(128) void rff_kernel(
    const float* __restrict__ Q, const float* __restrict__ omega,
    const float* __restrict__ brff, const float* __restrict__ mask,
    float* __restrict__ Phi)
{
  const int m = threadIdx.x;
  const int blk = blockIdx.x;
  const int nc = blk & 511;   // N/4 = 512
  const int bh = blk >> 9;
  const int b = bh >> 3, h = bh & 7;
  const int n0 = nc << 2;
  __shared__ float qs[4][64];
  {
    const int r = m >> 6, d = m & 63;
    qs[r][d]   = Q[((size_t)(b*N_) + n0 + r) * 512 + h*64 + d];
    qs[r+2][d] = Q[((size_t)(b*N_) + n0 + r + 2) * 512 + h*64 + d];
  }
  __syncthreads();
  float z0 = 0.f, z1 = 0.f, z2 = 0.f, z3 = 0.f;
#pragma unroll 4
  for (int d = 0; d < 64; ++d) {
    const float om = omega[d*M_ + m];
    z0 = fmaf(qs[0][d], om, z0);
    z1 = fmaf(qs[1][d], om, z1);
    z2 = fmaf(qs[2][d], om, z2);
    z3 = fmaf(qs[3][d], om, z3);
  }
  const float bm = brff[m];
  const float sc = 0.125f;  // sqrt(2/128)
  const size_t ob = ((size_t)bh * N_ + n0) * M_ + m;
  const int mb = b*N_ + n0;
  Phi[ob      ] = sc * cosf(z0 + bm) * mask[mb+0];
  Phi[ob + 128] = sc * cosf(z1 + bm) * mask[mb+1];
  Phi[ob + 256] = sc * cosf(z2 + bm) * mask[mb+2];
  Phi[ob + 384] = sc * cosf(z3 + bm) * mask[mb+3];
}

// ---------------------------------------------------------------------------
// Gram partial
// ---------------------------------------------------------------------------
__global__ __launch_bounds__(256) void gram_partial(
    const float* __restrict__ Phi, float* __restrict__ Part)
{
  const int bh = blockIdx.x, sp = blockIdx.y, tid = threadIdx.x;
  __shared__ alignas(16) float Ps[16][128];
  const int ty = tid >> 4, tx = tid & 15;
  float acc[8][8];
#pragma unroll
  for (int i = 0; i < 8; ++i)
#pragma unroll
    for (int j = 0; j < 8; ++j) acc[i][j] = 0.f;
  const int lrow = tid >> 4, lcol = (tid & 15) << 3;
  for (int n0 = sp*512; n0 < sp*512 + 512; n0 += 16) {
    float4 p0 = *(const float4*)(Phi + ((size_t)bh*N_ + n0 + lrow)*M_ + lcol);
    float4 p1 = *(const float4*)(Phi + ((size_t)bh*N_ + n0 + lrow)*M_ + lcol + 4);
    *(float4*)&Ps[lrow][lcol]   = p0;
    *(float4*)&Ps[lrow][lcol+4] = p1;
    __syncthreads();
#pragma unroll
    for (int kk = 0; kk < 16; ++kk) {
      float4 av0 = *(const float4*)&Ps[kk][ty*8];
      float4 av1 = *(const float4*)&Ps[kk][ty*8+4];
      float4 bv0 = *(const float4*)&Ps[kk][tx*8];
      float4 bv1 = *(const float4*)&Ps[kk][tx*8+4];
      float a[8] = {av0.x, av0.y, av0.z, av0.w, av1.x, av1.y, av1.z, av1.w};
      float b[8] = {bv0.x, bv0.y, bv0.z, bv0.w, bv1.x, bv1.y, bv1.z, bv1.w};
#pragma unroll
      for (int i = 0; i < 8; ++i)
#pragma unroll
        for (int j = 0; j < 8; ++j) acc[i][j] = fmaf(a[i], b[j], acc[i][j]);
    }
    __syncthreads();
  }
  const size_t ob = ((size_t)sp*64 + bh) * 16384;
#pragma unroll
  for (int i = 0; i < 8; ++i)
#pragma unroll
    for (int j = 0; j < 8; j += 4) {
      float4 o = {acc[i][j], acc[i][j+1], acc[i][j+2], acc[i][j+3]};
      *(float4*)(Part + ob + (size_t)(ty*8+i)*128 + tx*8 + j) = o;
    }
}

// ---------------------------------------------------------------------------
// PhiT V partial
// ---------------------------------------------------------------------------
__global__ __launch_bounds__(256) void phiTv_partial(
    const float* __restrict__ Phi, const float* __restrict__ V,
    float* __restrict__ Part)
{
  const int bh = blockIdx.x, sp = blockIdx.y, tid = threadIdx.x;
  const int b = bh >> 3, h = bh & 7;
  __shared__ alignas(16) float Ps[16][128];
  __shared__ alignas(16) float Vs[16][64];
  const int ty = tid >> 3, tx = tid & 7;
  float acc[4][8];
#pragma unroll
  for (int i = 0; i < 4; ++i)
#pragma unroll
    for (int j = 0; j < 8; ++j) acc[i][j] = 0.f;
  const int lrow = tid >> 4, lcol = (tid & 15) << 3;
  const int vrow = tid >> 3, vcol = (tid & 7) << 3;
  for (int n0 = sp*512; n0 < sp*512 + 512; n0 += 16) {
    float4 p0 = *(const float4*)(Phi + ((size_t)bh*N_ + n0 + lrow)*M_ + lcol);
    float4 p1 = *(const float4*)(Phi + ((size_t)bh*N_ + n0 + lrow)*M_ + lcol + 4);
    *(float4*)&Ps[lrow][lcol]   = p0;
    *(float4*)&Ps[lrow][lcol+4] = p1;
    if (tid < 128) {
      float4 v0 = *(const float4*)(V + ((size_t)(b*N_) + n0 + vrow)*512 + h*64 + vcol);
      float4 v1 = *(const float4*)(V + ((size_t)(b*N_) + n0 + vrow)*512 + h*64 + vcol + 4);
      *(float4*)&Vs[vrow][vcol]   = v0;
      *(float4*)&Vs[vrow][vcol+4] = v1;
    }
    __syncthreads();
#pragma unroll
    for (int kk = 0; kk < 16; ++kk) {
      float4 av = *(const float4*)&Ps[kk][ty*4];
      float4 bv0 = *(const float4*)&Vs[kk][tx*8];
      float4 bv1 = *(const float4*)&Vs[kk][tx*8+4];
      float a[4] = {av.x, av.y, av.z, av.w};
      float b[8] = {bv0.x, bv0.y, bv0.z, bv0.w, bv1.x, bv1.y, bv1.z, bv1.w};
#pragma unroll
      for (int i = 0; i < 4; ++i)
#pragma unroll
        for (int j = 0; j < 8; ++j) acc[i][j] = fmaf(a[i], b[j], acc[i][j]);
    }
    __syncthreads();
  }
  const size_t ob = ((size_t)sp*64 + bh) * 8192;
#pragma unroll
  for (int i = 0; i < 4; ++i)
#pragma unroll
    for (int j = 0; j < 8; j += 4) {
      float4 o = {acc[i][j], acc[i][j+1], acc[i][j+2], acc[i][j+3]};
      *(float4*)(Part + ob + (size_t)(ty*4+i)*64 + tx*8 + j) = o;
    }
}

// ---------------------------------------------------------------------------
__global__ __launch_bounds__(256) void reduce4_kernel(
    const float* __restrict__ part, float* __restrict__ out, int n, size_t cs)
{
  const int i = blockIdx.x * 256 + threadIdx.x;
  if (i < n) out[i] = (part[i] + part[cs + i]) + (part[2*cs + i] + part[3*cs + i]);
}

// ---------------------------------------------------------------------------
__global__ __launch_bounds__(256) void yy_kernel(
    const float* __restrict__ V, float* __restrict__ yy)
{
  const int bh = blockIdx.x, tid = threadIdx.x;
  const int b = bh >> 3, h = bh & 7;
  float s = 0.f;
  for (int t = tid; t < N_*64; t += 256) {
    const int n = t >> 6, d = t & 63;
    const float v = V[((size_t)(b*N_) + n)*512 + h*64 + d];
    s = fmaf(v, v, s);
  }
  __shared__ float red[256];
  red[tid] = s; __syncthreads();
  for (int st = 128; st > 0; st >>= 1) {
    if (tid < st) red[tid] += red[tid+st];
    __syncthreads();
  }
  if (tid == 0) yy[bh] = red[0];
}

// ---------------------------------------------------------------------------
// Blocked batched Cholesky (NB=16), 256 threads, XOR-swizzled LDS.
// Also writes Dinv[mat][bh][i] = 1/L[i][i] for the solver.
// Output written SYMMETRICALLY (upper = L^T).
// ---------------------------------------------------------------------------
#define EL(i,j) As[(((i) << 7) | ((j) ^ ((i) & 31)))]

__global__ __launch_bounds__(256) void chol4_kernel(
    const float* __restrict__ Gk, const float* __restrict__ Go, const float* __restrict__ Cq,
    float* __restrict__ Lk, float* __restrict__ Lo, float* __restrict__ LTq, float* __restrict__ LTk,
    float* __restrict__ ldbuf, float* __restrict__ Dinvb)
{
  __shared__ float As[128*128];
  const int bh = blockIdx.x, which = blockIdx.y, tid = threadIdx.x;
  const float* G1; const float* G2 = nullptr; float* Lout;
  if (which == 0)      { G1 = Gk; Lout = Lk;  }
  else if (which == 1) { G1 = Go; Lout = Lo;  }
  else if (which == 2) { G1 = Go; G2 = Cq; Lout = LTq; }
  else                 { G1 = Go; G2 = Gk; Lout = LTk; }
  const size_t base = (size_t)bh * 16384;
  for (int t = tid; t < 16384; t += 256) {
    float v = G1[base + t];
    if (G2) v = fmaf(5.f, G2[base + t], v);
    const int i = t >> 7, j = t & 127;
    if (i == j) v += 0.01f;
    EL(i, j) = v;
  }
  __syncthreads();

  float ldacc = 0.f;
  for (int kb = 0; kb < 8; ++kb) {
    const int k0 = kb << 4;
    const int rbase = k0 + 16;
    const int R = 128 - rbase;
    float Dg[16][16];
    float dinv[16];
    if (tid < 128) {
#pragma unroll
      for (int j = 0; j < 16; ++j)
#pragma unroll
        for (int p = 0; p < 16; ++p) if (p <= j) Dg[j][p] = EL(k0 + j, k0 + p);
#pragma unroll
      for (int kk = 0; kk < 16; ++kk) {
        const float d = sqrtf(Dg[kk][kk]);
        Dg[kk][kk] = d;
        const float di = 1.f / d;
        dinv[kk] = di;
#pragma unroll
        for (int r = 0; r < 16; ++r) if (r > kk) Dg[r][kk] *= di;
#pragma unroll
        for (int r = 0; r < 16; ++r) if (r > kk)
#pragma unroll
          for (int c2 = 0; c2 < 16; ++c2) if (c2 > kk && c2 <= r)
            Dg[r][c2] = fmaf(-Dg[r][kk], Dg[c2][kk], Dg[r][c2]);
      }
      if (tid == 0) {
#pragma unroll
        for (int kk = 0; kk < 16; ++kk) ldacc += logf(Dg[kk][kk]);
#pragma unroll
        for (int j = 0; j < 16; ++j)
#pragma unroll
          for (int p = 0; p < 16; ++p) if (p <= j) EL(k0 + j, k0 + p) = Dg[j][p];
      }
    }
    if (tid < R) {
      const int r = rbase + tid;
      float xr[16];
#pragma unroll
      for (int p = 0; p < 16; ++p) xr[p] = EL(r, k0 + p);
#pragma unroll
      for (int j = 0; j < 16; ++j) {
        float s = xr[j];
#pragma unroll
        for (int p = 0; p < 16; ++p) if (p < j) s = fmaf(-Dg[j][p], xr[p], s);
        xr[j] = s * dinv[j];
      }
#pragma unroll
      for (int p = 0; p < 16; ++p) EL(r, k0 + p) = xr[p];
    }
    __syncthreads();
    if (R > 0) {
      const int Rt = R >> 2;
      const int T = (Rt * (Rt + 1)) >> 1;
      for (int idx = tid; idx < T; idx += 256) {
        int ti = (int)((sqrtf(8.f * (float)idx + 1.f) - 1.f) * 0.5f);
        while (((ti + 1) * (ti + 2)) / 2 <= idx) ++ti;
        while ((ti * (ti + 1)) / 2 > idx) --ti;
        const int tj = idx - (ti * (ti + 1)) / 2;
        const int i0 = rbase + (ti << 2), j0 = rbase + (tj << 2);
        float Li[4][16], Lj[4][16], cc[4][4];
#pragma unroll
        for (int a = 0; a < 4; ++a)
#pragma unroll
          for (int p = 0; p < 16; ++p) Li[a][p] = EL(i0 + a, k0 + p);
#pragma unroll
        for (int bq2 = 0; bq2 < 4; ++bq2)
#pragma unroll
          for (int p = 0; p < 16; ++p) Lj[bq2][p] = EL(j0 + bq2, k0 + p);
#pragma unroll
        for (int a = 0; a < 4; ++a)
#pragma unroll
          for (int bq2 = 0; bq2 < 4; ++bq2) cc[a][bq2] = EL(i0 + a, j0 + bq2);
#pragma unroll
        for (int p = 0; p < 16; ++p)
#pragma unroll
          for (int a = 0; a < 4; ++a)
#pragma unroll
            for (int bq2 = 0; bq2 < 4; ++bq2)
              cc[a][bq2] = fmaf(-Li[a][p], Lj[bq2][p], cc[a][bq2]);
#pragma unroll
        for (int a = 0; a < 4; ++a)
#pragma unroll
          for (int bq2 = 0; bq2 < 4; ++bq2) EL(i0 + a, j0 + bq2) = cc[a][bq2];
      }
    }
    __syncthreads();
  }
  for (int t = tid; t < 16384; t += 256) {
    const int i = t >> 7, j = t & 127;
    Lout[base + t] = (j <= i) ? EL(i, j) : EL(j, i);
  }
  if (tid < 128) Dinvb[(size_t)which * 8192 + bh * 128 + tid] = 1.f / EL(tid, tid);
  if (tid == 0) ldbuf[which * 64 + bh] = 2.f * ldacc;
}

// ---------------------------------------------------------------------------
// Blocked batched cho_solve (NB=16), 256 threads.
// Per kb-block: coop panel load -> LDS; diag solve (1 thread/RHS col, diag
// reciprocals precomputed); rank-16 trailing update as parallel float4 GEMM.
// Upper half of Lsrc holds L^T, so backward pass reads contiguous rows too.
// ---------------------------------------------------------------------------
__global__ __launch_bounds__(256) void solve5_kernel(
    const float* __restrict__ Lk, const float* __restrict__ Lo,
    const float* __restrict__ LTq, const float* __restrict__ LTk,
    const float* __restrict__ Dinvb,
    const float* __restrict__ PkTv, const float* __restrict__ PhiTy,
    const float* __restrict__ Cq, const float* __restrict__ Gk,
    float* __restrict__ Z1, float* __restrict__ Aoi,
    float* __restrict__ Z2, float* __restrict__ Wq2, float* __restrict__ Wk2)
{
  __shared__ alignas(16) float Xs[128][128];
  __shared__ alignas(16) float Lp[128][16];
  __shared__ float di[128];
  const int bh = blockIdx.x, which = blockIdx.y, tid = threadIdx.x;
  const float* Lsrc; const float* Bsrc; float* Out; int nr; int mat;
  if (which == 0)      { Lsrc = Lk;  Bsrc = PkTv;    Out = Z1;  nr = 64;  mat = 0; }
  else if (which == 1) { Lsrc = Lo;  Bsrc = nullptr; Out = Aoi; nr = 128; mat = 1; }
  else if (which == 2) { Lsrc = LTq; Bsrc = PhiTy;   Out = Z2;  nr = 64;  mat = 2; }
  else if (which == 3) { Lsrc = LTq; Bsrc = Cq;      Out = Wq2; nr = 128; mat = 2; }
  else                 { Lsrc = LTk; Bsrc = Gk;      Out = Wk2; nr = 128; mat = 3; }
  const size_t baseL = (size_t)bh * 16384;
  const size_t baseB = (size_t)bh * 128 * (size_t)nr;
  const int sh = (nr == 64) ? 6 : 7, mk = nr - 1;
  if (Bsrc) {
    for (int t = tid; t < 128 * nr; t += 256) Xs[t >> sh][t & mk] = Bsrc[baseB + t];
  } else {
    for (int t = tid; t < 16384; t += 256)
      Xs[t >> 7][t & 127] = ((t >> 7) == (t & 127)) ? 1.f : 0.f;
  }
  if (tid < 128) di[tid] = Dinvb[(size_t)mat * 8192 + bh * 128 + tid];
  const int c0 = (nr == 128) ? ((tid & 31) << 2) : ((tid & 15) << 2);
  const int rg = (nr == 128) ? (tid >> 5) : (tid >> 4);
  const int rstride = (nr == 128) ? 8 : 16;
  __syncthreads();
  // ===== forward: L y = b =====
  for (int kb = 0; kb < 8; ++kb) {
    const int k0 = kb << 4;
    const int nrow = 128 - k0;
    for (int t = tid; t < nrow * 4; t += 256) {
      const int pr = t >> 2, pc = (t & 3) << 2;
      *(float4*)&Lp[pr][pc] = *(const float4*)(Lsrc + baseL + (size_t)(k0 + pr) * 128 + k0 + pc);
    }
    __syncthreads();
    if (tid < nr) {
      float xb[16];
#pragma unroll
      for (int j = 0; j < 16; ++j) {
        float s = Xs[k0 + j][tid];
#pragma unroll
        for (int p = 0; p < 16; ++p) if (p < j) s = fmaf(-Lp[j][p], xb[p], s);
        xb[j] = s * di[k0 + j];
        Xs[k0 + j][tid] = xb[j];
      }
    }
    __syncthreads();
    if (k0 + 16 < 128) {
      float4 xb4[16];
#pragma unroll
      for (int p = 0; p < 16; ++p) xb4[p] = *(const float4*)&Xs[k0 + p][c0];
      for (int r = k0 + 16 + rg; r < 128; r += rstride) {
        float4 xv = *(const float4*)&Xs[r][c0];
#pragma unroll
        for (int p = 0; p < 16; ++p) {
          const float l = Lp[r - k0][p];
          xv.x = fmaf(-l, xb4[p].x, xv.x);
          xv.y = fmaf(-l, xb4[p].y, xv.y);
          xv.z = fmaf(-l, xb4[p].z, xv.z);
          xv.w = fmaf(-l, xb4[p].w, xv.w);
        }
        *(float4*)&Xs[r][c0] = xv;
      }
    }
    __syncthreads();
  }
  // ===== backward: L^T x = y =====
  for (int kb = 7; kb >= 0; --kb) {
    const int k0 = kb << 4;
    const int nrow = k0 + 16;
    for (int t = tid; t < nrow * 4; t += 256) {
      const int pr = t >> 2, pc = (t & 3) << 2;
      *(float4*)&Lp[pr][pc] = *(const float4*)(Lsrc + baseL + (size_t)pr * 128 + k0 + pc);
    }
    __syncthreads();
    if (tid < nr) {
      float xb[16];
#pragma unroll
      for (int j = 15; j >= 0; --j) {
        float s = Xs[k0 + j][tid];
#pragma unroll
        for (int p = 0; p < 16; ++p) if (p > j) s = fmaf(-Lp[k0 + j][p], xb[p], s);
        xb[j] = s * di[k0 + j];
        Xs[k0 + j][tid] = xb[j];
      }
    }
    __syncthreads();
    if (k0 > 0) {
      float4 xb4[16];
#pragma unroll
      for (int p = 0; p < 16; ++p) xb4[p] = *(const float4*)&Xs[k0 + p][c0];
      for (int r = rg; r < k0; r += rstride) {
        float4 xv = *(const float4*)&Xs[r][c0];
#pragma unroll
        for (int p = 0; p < 16; ++p) {
          const float l = Lp[r][p];
          xv.x = fmaf(-l, xb4[p].x, xv.x);
          xv.y = fmaf(-l, xb4[p].y, xv.y);
          xv.z = fmaf(-l, xb4[p].z, xv.z);
          xv.w = fmaf(-l, xb4[p].w, xv.w);
        }
        *(float4*)&Xs[r][c0] = xv;
      }
    }
    __syncthreads();
  }
  for (int t = tid; t < 128 * nr; t += 256) Out[baseB + t] = Xs[t >> sh][t & mk];
}

// ---------------------------------------------------------------------------
// mid = Z1 - 0.01 * Aoi @ Z1   (Aoi symmetric)
// ---------------------------------------------------------------------------
__global__ __launch_bounds__(256) void mid_kernel(
    const float* __restrict__ Aoi, const float* __restrict__ Z1,
    float* __restrict__ midb)
{
  __shared__ alignas(16) float Ao[128][128];
  __shared__ alignas(16) float Z[128][64];
  const int bh = blockIdx.x, tid = threadIdx.x;
  const size_t bM = (size_t)bh * 16384, bD = (size_t)bh * 8192;
  for (int t4 = tid; t4 < 4096; t4 += 256) {
    const int r = t4 >> 5, c4 = (t4 & 31) << 2;
    *(float4*)&Ao[r][c4] = *(const float4*)(Aoi + bM + (size_t)r*128 + c4);
  }
  for (int t4 = tid; t4 < 2048; t4 += 256) {
    const int r = t4 >> 4, c4 = (t4 & 15) << 2;
    *(float4*)&Z[r][c4] = *(const float4*)(Z1 + bD + (size_t)r*64 + c4);
  }
  __syncthreads();
  const int ty = tid >> 4, tx = tid & 15;
  float acc[8][4];
#pragma unroll
  for (int i = 0; i < 8; ++i)
#pragma unroll
    for (int j = 0; j < 4; ++j) acc[i][j] = 0.f;
  for (int kk = 0; kk < 128; ++kk) {
    float4 a0 = *(const float4*)&Ao[kk][ty*8];
    float4 a1 = *(const float4*)&Ao[kk][ty*8+4];
    float4 bv = *(const float4*)&Z[kk][tx*4];
    float a[8] = {a0.x, a0.y, a0.z, a0.w, a1.x, a1.y, a1.z, a1.w};
    float b[4] = {bv.x, bv.y, bv.z, bv.w};
#pragma unroll
    for (int i = 0; i < 8; ++i)
#pragma unroll
      for (int j = 0; j < 4; ++j) acc[i][j] = fmaf(a[i], b[j], acc[i][j]);
  }
#pragma unroll
  for (int i = 0; i < 8; ++i) {
    const int r = ty*8 + i, c = tx*4;
    float4 o;
    o.x = Z[r][c+0] - 0.01f*acc[i][0];
    o.y = Z[r][c+1] - 0.01f*acc[i][1];
    o.z = Z[r][c+2] - 0.01f*acc[i][2];
    o.w = Z[r][c+3] - 0.01f*acc[i][3];
    *(float4*)(midb + bD + (size_t)r*64 + c) = o;
  }
}

// ---------------------------------------------------------------------------
// Pq = Cq @ Wq2 ; Pk = Gk @ Wk2   (A operand symmetric)
// ---------------------------------------------------------------------------
__global__ __launch_bounds__(256) void pmat_kernel(
    const float* __restrict__ Cq, const float* __restrict__ Wq2,
    const float* __restrict__ Gk, const float* __restrict__ Wk2,
    float* __restrict__ Pq, float* __restrict__ Pk)
{
  __shared__ alignas(16) float Am[128][128];
  __shared__ alignas(16) float Bm[128][128];
  const int bh = blockIdx.x, which = blockIdx.y, tid = threadIdx.x;
  const float* Ap = which ? Gk : Cq;
  const float* Bp = which ? Wk2 : Wq2;
  float* Op = which ? Pk : Pq;
  const size_t base = (size_t)bh * 16384;
  for (int t4 = tid; t4 < 4096; t4 += 256) {
    const int r = t4 >> 5, c4 = (t4 & 31) << 2;
    *(float4*)&Am[r][c4] = *(const float4*)(Ap + base + (size_t)r*128 + c4);
    *(float4*)&Bm[r][c4] = *(const float4*)(Bp + base + (size_t)r*128 + c4);
  }
  __syncthreads();
  const int ty = tid >> 4, tx = tid & 15;
  float acc[8][8];
#pragma unroll
  for (int i = 0; i < 8; ++i)
#pragma unroll
    for (int j = 0; j < 8; ++j) acc[i][j] = 0.f;
  for (int kk = 0; kk < 128; ++kk) {
    float4 av0 = *(const float4*)&Am[kk][ty*8];
    float4 av1 = *(const float4*)&Am[kk][ty*8+4];
    float4 bv0 = *(const float4*)&Bm[kk][tx*8];
    float4 bv1 = *(const float4*)&Bm[kk][tx*8+4];
    float a[8] = {av0.x, av0.y, av0.z, av0.w, av1.x, av1.y, av1.z, av1.w};
    float b[8] = {bv0.x, bv0.y, bv0.z, bv0.w, bv1.x, bv1.y, bv1.z, bv1.w};
#pragma unroll
    for (int i = 0; i < 8; ++i)
#pragma unroll
      for (int j = 0; j < 8; ++j) acc[i][j] = fmaf(a[i], b[j], acc[i][j]);
  }
#pragma unroll
  for (int i = 0; i < 8; ++i)
#pragma unroll
    for (int j = 0; j < 8; j += 4) {
      float4 o = {acc[i][j], acc[i][j+1], acc[i][j+2], acc[i][j+3]};
      *(float4*)(Op + base + (size_t)(ty*8+i)*128 + tx*8 + j) = o;
    }
}

// ---------------------------------------------------------------------------
__global__ __launch_bounds__(256) void scalars_kernel(
    const float* __restrict__ Aoi, const float* __restrict__ Cq, const float* __restrict__ Gk,
    const float* __restrict__ Pq, const float* __restrict__ Pk, const float* __restrict__ Wk2,
    const float* __restrict__ PhiTy, const float* __restrict__ Z2,
    const float* __restrict__ yyb, const float* __restrict__ ldb,
    float* __restrict__ regp)
{
  const int bh = blockIdx.x, tid = threadIdx.x;
  const size_t b0 = (size_t)bh * 16384, b1 = (size_t)bh * 8192;
  double aoCq=0, aoGk=0, aoPq=0, aoPk=0, wkGk=0, trCq=0, trGk=0, trPq=0, trPk=0, s1=0;
  for (int t = tid; t < 16384; t += 256) {
    const double ao = Aoi[b0+t], cq = Cq[b0+t], gk = Gk[b0+t];
    const double pq = Pq[b0+t], pk = Pk[b0+t], wk = Wk2[b0+t];
    aoCq += ao*cq; aoGk += ao*gk; aoPq += ao*pq; aoPk += ao*pk; wkGk += wk*gk;
    if (t % 129 == 0) { trCq += cq; trGk += gk; trPq += pq; trPk += pk; }
  }
  for (int t = tid; t < 8192; t += 256) s1 += (double)PhiTy[b1+t] * (double)Z2[b1+t];
  __shared__ double red[256];
  double vals[10] = {aoCq, aoGk, aoPq, aoPk, wkGk, trCq, trGk, trPq, trPk, s1};
  double tot[10];
  for (int vv = 0; vv < 10; ++vv) {
    red[tid] = vals[vv];
    __syncthreads();
    for (int st = 128; st > 0; st >>= 1) {
      if (tid < st) red[tid] += red[tid+st];
      __syncthreads();
    }
    tot[vv] = red[0];
    __syncthreads();
  }
  if (tid == 0) {
    const double D = 64.0, Nd = 2048.0;
    const double ldAo = ldb[64 + bh], ldTq = ldb[128 + bh], ldTk = ldb[192 + bh];
    const double yv = yyb[bh];
    const double cst  = Nd * log(2.0 * 3.14159265358979323846);
    const double leps = Nd * log(0.002);
    const double datq = 500.0*yv - 2500.0*tot[9];
    const double modq = D*(500.0*tot[5] - 2500.0*tot[7] - 0.01*(500.0*tot[0] - 2500.0*tot[2]));
    const double ldq  = leps + ldTq - ldAo;
    const double LBq  = -0.5*(datq + modq + ldq + cst);
    const double datk = D*(500.0*tot[6] - 2500.0*tot[4]);
    const double modk = D*(500.0*tot[6] - 2500.0*tot[8] - 0.01*(500.0*tot[1] - 2500.0*tot[3]));
    const double ldk  = leps + ldTk - ldAo;
    const double LBk  = -0.5*(datk + modk + ldk + cst);
    regp[bh] = (float)(-(LBq + LBk) / 64.0);
  }
}

__global__ void regfinal_kernel(const float* __restrict__ regp, float* __restrict__ outp)
{
  __shared__ float red[64];
  const int tid = threadIdx.x;
  red[tid] = regp[tid];
  __syncthreads();
  for (int st = 32; st > 0; st >>= 1) {
    if (tid < st) red[tid] += red[tid+st];
    __syncthreads();
  }
  if (tid == 0) outp[0] = red[0];
}

// ---------------------------------------------------------------------------
// y = Phi_q @ mid
// ---------------------------------------------------------------------------
__global__ __launch_bounds__(256) void y_kernel(
    const float* __restrict__ Phi, const float* __restrict__ midb,
    float* __restrict__ Yatt)
{
  __shared__ alignas(16) float Ps[128][128];
  __shared__ alignas(16) float Ms[128][64];
  const int blk = blockIdx.x;
  const int bh = blk >> 4, nt = blk & 15;
  const int b = bh >> 3, h = bh & 7;
  const int n0 = nt << 7;
  const int tid = threadIdx.x;
  for (int t4 = tid; t4 < 4096; t4 += 256) {
    const int r = t4 >> 5, c4 = (t4 & 31) << 2;
    *(float4*)&Ps[r][c4] = *(const float4*)(Phi + ((size_t)bh*N_ + n0 + r)*M_ + c4);
  }
  for (int t4 = tid; t4 < 2048; t4 += 256) {
    const int r = t4 >> 4, c4 = (t4 & 15) << 2;
    *(float4*)&Ms[r][c4] = *(const float4*)(midb + (size_t)bh*8192 + (size_t)r*64 + c4);
  }
  __syncthreads();
  const int ty = tid >> 4, tx = tid & 15;
  float acc[8][4];
#pragma unroll
  for (int i = 0; i < 8; ++i)
#pragma unroll
    for (int j = 0; j < 4; ++j) acc[i][j] = 0.f;
  for (int kk = 0; kk < 128; ++kk) {
    float4 bv = *(const float4*)&Ms[kk][tx*4];
    float b[4] = {bv.x, bv.y, bv.z, bv.w};
#pragma unroll
    for (int i = 0; i < 8; ++i) {
      const float a = Ps[ty*8+i][kk];
      acc[i][0] = fmaf(a, b[0], acc[i][0]);
      acc[i][1] = fmaf(a, b[1], acc[i][1]);
      acc[i][2] = fmaf(a, b[2], acc[i][2]);
      acc[i][3] = fmaf(a, b[3], acc[i][3]);
    }
  }
#pragma unroll
  for (int i = 0; i < 8; ++i) {
    float4 o = {acc[i][0], acc[i][1], acc[i][2], acc[i][3]};
    *(float4*)(Yatt + ((size_t)(b*N_) + n0 + ty*8 + i)*512 + h*64 + tx*4) = o;
  }
}

// ---------------------------------------------------------------------------
extern "C" void kernel_launch(void* const* d_in, const int* in_sizes, int n_in,
                              void* d_out, int out_size, void* d_ws, size_t ws_size,
                              hipStream_t stream)
{
  const float* x     = (const float*)d_in[0];
  const float* mask  = (const float*)d_in[1];
  const float* Wq    = (const float*)d_in[2];
  const float* bq    = (const float*)d_in[3];
  const float* Wk    = (const float*)d_in[4];
  const float* bk    = (const float*)d_in[5];
  const float* Wv    = (const float*)d_in[6];
  const float* bv    = (const float*)d_in[7];
  const float* Wx0   = (const float*)d_in[8];
  const float* bx0   = (const float*)d_in[9];
  const float* Wo    = (const float*)d_in[10];
  const float* bo    = (const float*)d_in[11];
  const float* omega = (const float*)d_in[12];
  const float* brff  = (const float*)d_in[13];
  float* outp = (float*)d_out;

  float* W_ = (float*)d_ws;
  size_t off = 0;
  auto take = [&](size_t n) -> float* { float* p = W_ + off; off += n; return p; };
  const size_t SZ_BNH = (size_t)8*2048*512;    // 8,388,608
  const size_t SZ_PHI = (size_t)64*2048*128;   // 16,777,216
  const size_t SZ_MM  = (size_t)64*128*128;    // 1,048,576
  const size_t SZ_MD  = (size_t)64*128*64;     //   524,288

  float* tmp  = take(SZ_BNH);   // q/k/x0 heads; later Yat
  float* vb   = take(SZ_BNH);
  float* Phi  = take(SZ_PHI);
  unsigned short* Xhi = (unsigned short*)take(SZ_BNH/2);   // bf16 x-hi (later y-hi)
  unsigned short* Xlo = (unsigned short*)take(SZ_BNH/2);   // bf16 x-lo (later y-lo)
  unsigned short* Wsp = (unsigned short*)take((size_t)5*524288/2); // 5x (hi 262144 + lo 262144)
  float* Gk   = take(SZ_MM);
  float* Go   = take(SZ_MM);
  float* Cq   = take(SZ_MM);
  float* Lk   = take(SZ_MM);
  float* Lo   = take(SZ_MM);
  float* LTq  = take(SZ_MM);
  float* LTk  = take(SZ_MM);
  float* Aoi  = take(SZ_MM);
  float* Wq2  = take(SZ_MM);
  float* Wk2  = take(SZ_MM);
  float* Pq   = take(SZ_MM);
  float* Pk   = take(SZ_MM);
  float* PkTv = take(SZ_MD);
  float* PhiTy= take(SZ_MD);
  float* Z1   = take(SZ_MD);
  float* Z2   = take(SZ_MD);
  float* midb = take(SZ_MD);
  float* Part = take(4*SZ_MM);
  float* Dinv = take(4*64*128);
  float* yyb  = take(64);
  float* ldb  = take(256);
  float* regp = take(64);
  (void)ws_size; (void)in_sizes; (void)n_in; (void)out_size;

  unsigned short* WH0 = Wsp + 0*524288;            // Wq hi
  unsigned short* WL0 = Wsp + 0*524288 + 262144;   // Wq lo
  unsigned short* WH1 = Wsp + 1*524288;            // Wk
  unsigned short* WL1 = Wsp + 1*524288 + 262144;
  unsigned short* WH2 = Wsp + 2*524288;            // Wv
  unsigned short* WL2 = Wsp + 2*524288 + 262144;
  unsigned short* WH3 = Wsp + 3*524288;            // Wx0
  unsigned short* WL3 = Wsp + 3*524288 + 262144;
  unsigned short* WH4 = Wsp + 4*524288;            // Wo
  unsigned short* WL4 = Wsp + 4*524288 + 262144;

  // split inputs to bf16 hi/lo
  split_kernel<<<8192, 256, 0, stream>>>(x, Xhi, Xlo, (int)SZ_BNH);
  split_kernel<<<256, 256, 0, stream>>>(Wq,  WH0, WL0, 262144);
  split_kernel<<<256, 256, 0, stream>>>(Wk,  WH1, WL1, 262144);
  split_kernel<<<256, 256, 0, stream>>>(Wv,  WH2, WL2, 262144);
  split_kernel<<<256, 256, 0, stream>>>(Wx0, WH3, WL3, 262144);
  split_kernel<<<256, 256, 0, stream>>>(Wo,  WH4, WL4, 262144);

  // x0 path -> Go
  gemm_mfma<<<512, 256, 0, stream>>>(Xhi, Xlo, WH3, WL3, bx0, nullptr, tmp);
  rff_kernel<<<32768, 128, 0, stream>>>(tmp, omega, brff, mask, Phi);
  gram_partial<<<dim3(64,4), 256, 0, stream>>>(Phi, Part);
  reduce4_kernel<<<4096, 256, 0, stream>>>(Part, Go, 1048576, (size_t)1048576);
  // k path -> Gk, PkTv
  gemm_mfma<<<512, 256, 0, stream>>>(Xhi, Xlo, WH1, WL1, bk, nullptr, tmp);
  rff_kernel<<<32768, 128, 0, stream>>>(tmp, omega, brff, mask, Phi);
  gram_partial<<<dim3(64,4), 256, 0, stream>>>(Phi, Part);
  reduce4_kernel<<<4096, 256, 0, stream>>>(Part, Gk, 1048576, (size_t)1048576);
  gemm_mfma<<<512, 256, 0, stream>>>(Xhi, Xlo, WH2, WL2, bv, mask, vb);
  phiTv_partial<<<dim3(64,4), 256, 0, stream>>>(Phi, vb, Part);
  reduce4_kernel<<<2048, 256, 0, stream>>>(Part, PkTv, 524288, (size_t)524288);
  // q path -> Cq, PhiTy
  gemm_mfma<<<512, 256, 0, stream>>>(Xhi, Xlo, WH0, WL0, bq, nullptr, tmp);
  rff_kernel<<<32768, 128, 0, stream>>>(tmp, omega, brff, mask, Phi);
  gram_partial<<<dim3(64,4), 256, 0, stream>>>(Phi, Part);
  reduce4_kernel<<<4096, 256, 0, stream>>>(Part, Cq, 1048576, (size_t)1048576);
  phiTv_partial<<<dim3(64,4), 256, 0, stream>>>(Phi, vb, Part);
  reduce4_kernel<<<2048, 256, 0, stream>>>(Part, PhiTy, 524288, (size_t)524288);
  yy_kernel<<<64, 256, 0, stream>>>(vb, yyb);
  // batched linear algebra
  chol4_kernel<<<dim3(64,4), 256, 0, stream>>>(Gk, Go, Cq, Lk, Lo, LTq, LTk, ldb, Dinv);
  solve5_kernel<<<dim3(64,5), 256, 0, stream>>>(Lk, Lo, LTq, LTk, Dinv, PkTv, PhiTy, Cq, Gk,
                                                Z1, Aoi, Z2, Wq2, Wk2);
  mid_kernel<<<64, 256, 0, stream>>>(Aoi, Z1, midb);
  pmat_kernel<<<dim3(64,2), 256, 0, stream>>>(Cq, Wq2, Gk, Wk2, Pq, Pk);
  scalars_kernel<<<64, 256, 0, stream>>>(Aoi, Cq, Gk, Pq, Pk, Wk2, PhiTy, Z2, yyb, ldb, regp);
  regfinal_kernel<<<1, 64, 0, stream>>>(regp, outp + SZ_BNH);
  // output path: y -> tmp, split, project with Wo
  y_kernel<<<1024, 256, 0, stream>>>(Phi, midb, tmp);
  split_kernel<<<8192, 256, 0, stream>>>(tmp, Xhi, Xlo, (int)SZ_BNH);
  gemm_mfma<<<512, 256, 0, stream>>>(Xhi, Xlo, WH4, WL4, bo, nullptr, outp);
}

// Round 4
// 1050.102 us; speedup vs baseline: 2.3797x; 1.0494x over previous
//
#include <hip/hip_runtime.h>
#include <math.h>

// Problem constants
#define B_ 8
#define N_ 2048
#define HD_ 512
#define H_ 8
#define M_ 128
#define VD_ 64
// LAM = 0.01, EPS = 0.002 ; LAM/EPS = 5 ; 1/EPS = 500 ; 1/(100*EPS^2) = 2500

typedef __attribute__((ext_vector_type(8))) short short8v;   // 8 bf16 (4 VGPRs)
typedef __attribute__((ext_vector_type(4))) float f32x4;

__device__ __forceinline__ unsigned short f2bf(float f) {
  unsigned u = __float_as_uint(f);
  u += 0x7FFF + ((u >> 16) & 1);   // round-to-nearest-even
  return (unsigned short)(u >> 16);
}
__device__ __forceinline__ float bf2f(unsigned short h) {
  return __uint_as_float(((unsigned)h) << 16);
}

// ---------------------------------------------------------------------------
// Split fp32 -> (hi, lo) bf16 pair: hi = bf16(a), lo = bf16(a - hi).
// ---------------------------------------------------------------------------
__global__ __launch_bounds__(256) void split_kernel(
    const float* __restrict__ in, unsigned short* __restrict__ hi,
    unsigned short* __restrict__ lo, int n)
{
  const int i = (blockIdx.x * 256 + threadIdx.x) << 2;
  if (i >= n) return;
  float4 v = *(const float4*)(in + i);
  ushort4 h, l;
  h.x = f2bf(v.x); l.x = f2bf(v.x - bf2f(h.x));
  h.y = f2bf(v.y); l.y = f2bf(v.y - bf2f(h.y));
  h.z = f2bf(v.z); l.z = f2bf(v.z - bf2f(h.z));
  h.w = f2bf(v.w); l.w = f2bf(v.w - bf2f(h.w));
  *(ushort4*)(hi + i) = h;
  *(ushort4*)(lo + i) = l;
}

// ---------------------------------------------------------------------------
// bf16x3 MFMA GEMM: Y[r,c] = sum_k A[r,k]*B[c,k] + bias[c], optional rowscale.
// ---------------------------------------------------------------------------
#define LDP 40
__global__ __launch_bounds__(256) void gemm_mfma(
    const unsigned short* __restrict__ Ahi, const unsigned short* __restrict__ Alo,
    const unsigned short* __restrict__ Bhi, const unsigned short* __restrict__ Blo,
    const float* __restrict__ bias, const float* __restrict__ rowscale,
    float* __restrict__ Y)
{
  __shared__ unsigned short Ah[128 * LDP], Al[128 * LDP];
  __shared__ unsigned short Bh[128 * LDP], Bl[128 * LDP];
  const int tid = threadIdx.x;
  const int bx = blockIdx.x & 3, by = blockIdx.x >> 2;
  const int row0 = by << 7, col0 = bx << 7;
  const int lane = tid & 63, wave = tid >> 6;
  const int wr = wave >> 1, wc = wave & 1;
  const int fr = lane & 15, fk = (lane >> 4) << 3;
  f32x4 acc[4][4];
#pragma unroll
  for (int i = 0; i < 4; ++i)
#pragma unroll
    for (int j = 0; j < 4; ++j) acc[i][j] = (f32x4){0.f, 0.f, 0.f, 0.f};

  const int srow = tid >> 2;          // 0..63
  const int sch = (tid & 3) << 3;     // 0,8,16,24
  const size_t ga = (size_t)(row0 + srow) * 512 + sch;
  const size_t gb = (size_t)(col0 + srow) * 512 + sch;

  short8v rah0, rah1, ral0, ral1, rbh0, rbh1, rbl0, rbl1;
#define LOADREGS(k)                                                          \
  rah0 = *(const short8v*)(Ahi + ga + (k));                                  \
  rah1 = *(const short8v*)(Ahi + ga + (size_t)64 * 512 + (k));               \
  ral0 = *(const short8v*)(Alo + ga + (k));                                  \
  ral1 = *(const short8v*)(Alo + ga + (size_t)64 * 512 + (k));               \
  rbh0 = *(const short8v*)(Bhi + gb + (k));                                  \
  rbh1 = *(const short8v*)(Bhi + gb + (size_t)64 * 512 + (k));               \
  rbl0 = *(const short8v*)(Blo + gb + (k));                                  \
  rbl1 = *(const short8v*)(Blo + gb + (size_t)64 * 512 + (k));

  LOADREGS(0)
  for (int kt = 0; kt < 16; ++kt) {
    __syncthreads();   // previous tile's compute done
    *(short8v*)&Ah[srow * LDP + sch] = rah0;
    *(short8v*)&Ah[(srow + 64) * LDP + sch] = rah1;
    *(short8v*)&Al[srow * LDP + sch] = ral0;
    *(short8v*)&Al[(srow + 64) * LDP + sch] = ral1;
    *(short8v*)&Bh[srow * LDP + sch] = rbh0;
    *(short8v*)&Bh[(srow + 64) * LDP + sch] = rbh1;
    *(short8v*)&Bl[srow * LDP + sch] = rbl0;
    *(short8v*)&Bl[(srow + 64) * LDP + sch] = rbl1;
    __syncthreads();
    if (kt < 15) { LOADREGS((kt + 1) * 32) }   // prefetch overlaps MFMA
    short8v a_hi[4], a_lo[4];
#pragma unroll
    for (int i = 0; i < 4; ++i) {
      const int ar = (wr * 64 + i * 16 + fr) * LDP + fk;
      a_hi[i] = *(const short8v*)&Ah[ar];
      a_lo[i] = *(const short8v*)&Al[ar];
    }
#pragma unroll
    for (int j = 0; j < 4; ++j) {
      const int br = (wc * 64 + j * 16 + fr) * LDP + fk;
      short8v b_hi = *(const short8v*)&Bh[br];
      short8v b_lo = *(const short8v*)&Bl[br];
#pragma unroll
      for (int i = 0; i < 4; ++i) {
        acc[i][j] = __builtin_amdgcn_mfma_f32_16x16x32_bf16(a_hi[i], b_hi, acc[i][j], 0, 0, 0);
        acc[i][j] = __builtin_amdgcn_mfma_f32_16x16x32_bf16(a_hi[i], b_lo, acc[i][j], 0, 0, 0);
        acc[i][j] = __builtin_amdgcn_mfma_f32_16x16x32_bf16(a_lo[i], b_hi, acc[i][j], 0, 0, 0);
      }
    }
  }
  // epilogue: C/D layout col = lane&15, row = (lane>>4)*4 + reg
  const int rbase = row0 + wr * 64 + ((lane >> 4) << 2);
#pragma unroll
  for (int j = 0; j < 4; ++j) {
    const int col = col0 + wc * 64 + j * 16 + fr;
    const float bc = bias[col];
#pragma unroll
    for (int i = 0; i < 4; ++i) {
      const int r0 = rbase + i * 16;
#pragma unroll
      for (int r = 0; r < 4; ++r) {
        float v = acc[i][j][r] + bc;
        if (rowscale) v *= rowscale[r0 + r];
        Y[(size_t)(r0 + r) * 512 + col] = v;
      }
    }
  }
}
#undef LOADREGS

// ---------------------------------------------------------------------------
// RFF (32 rows/block): Phi[bh,n,m] = 0.125*cos(q.omega + brff[m]) * mask[b,n]
// omega traffic amortized 8x vs 4-row version.
// ---------------------------------------------------------------------------
__global__ __launch_bounds__(128) void rff_kernel(
    const float* __restrict__ Q, const float* __restrict__ omega,
    const float* __restrict__ brff, const float* __restrict__ mask,
    float* __restrict__ Phi)
{
  const int m = threadIdx.x;
  const int blk = blockIdx.x;      // 64 bh * 64 chunks
  const int ch = blk & 63;
  const int bh = blk >> 6;
  const int b = bh >> 3, h = bh & 7;
  const int n0 = ch << 5;
  __shared__ float qs[32][64];
  for (int t = m; t < 2048; t += 128) {
    const int r = t >> 6, d = t & 63;
    qs[r][d] = Q[((size_t)(b * N_) + n0 + r) * 512 + h * 64 + d];
  }
  __syncthreads();
  float z[32];
#pragma unroll
  for (int r = 0; r < 32; ++r) z[r] = 0.f;
#pragma unroll 4
  for (int d = 0; d < 64; ++d) {
    const float om = omega[d * M_ + m];
#pragma unroll
    for (int r = 0; r < 32; ++r) z[r] = fmaf(qs[r][d], om, z[r]);
  }
  const float bm = brff[m];
  const size_t ob = ((size_t)bh * N_ + n0) * M_ + m;
#pragma unroll
  for (int r = 0; r < 32; ++r) {
    Phi[ob + (size_t)r * 128] = 0.125f * cosf(z[r] + bm) * mask[b * N_ + n0 + r];
  }
}

// ---------------------------------------------------------------------------
// Gram partial
// ---------------------------------------------------------------------------
__global__ __launch_bounds__(256) void gram_partial(
    const float* __restrict__ Phi, float* __restrict__ Part)
{
  const int bh = blockIdx.x, sp = blockIdx.y, tid = threadIdx.x;
  __shared__ alignas(16) float Ps[16][128];
  const int ty = tid >> 4, tx = tid & 15;
  float acc[8][8];
#pragma unroll
  for (int i = 0; i < 8; ++i)
#pragma unroll
    for (int j = 0; j < 8; ++j) acc[i][j] = 0.f;
  const int lrow = tid >> 4, lcol = (tid & 15) << 3;
  for (int n0 = sp*512; n0 < sp*512 + 512; n0 += 16) {
    float4 p0 = *(const float4*)(Phi + ((size_t)bh*N_ + n0 + lrow)*M_ + lcol);
    float4 p1 = *(const float4*)(Phi + ((size_t)bh*N_ + n0 + lrow)*M_ + lcol + 4);
    *(float4*)&Ps[lrow][lcol]   = p0;
    *(float4*)&Ps[lrow][lcol+4] = p1;
    __syncthreads();
#pragma unroll
    for (int kk = 0; kk < 16; ++kk) {
      float4 av0 = *(const float4*)&Ps[kk][ty*8];
      float4 av1 = *(const float4*)&Ps[kk][ty*8+4];
      float4 bv0 = *(const float4*)&Ps[kk][tx*8];
      float4 bv1 = *(const float4*)&Ps[kk][tx*8+4];
      float a[8] = {av0.x, av0.y, av0.z, av0.w, av1.x, av1.y, av1.z, av1.w};
      float b[8] = {bv0.x, bv0.y, bv0.z, bv0.w, bv1.x, bv1.y, bv1.z, bv1.w};
#pragma unroll
      for (int i = 0; i < 8; ++i)
#pragma unroll
        for (int j = 0; j < 8; ++j) acc[i][j] = fmaf(a[i], b[j], acc[i][j]);
    }
    __syncthreads();
  }
  const size_t ob = ((size_t)sp*64 + bh) * 16384;
#pragma unroll
  for (int i = 0; i < 8; ++i)
#pragma unroll
    for (int j = 0; j < 8; j += 4) {
      float4 o = {acc[i][j], acc[i][j+1], acc[i][j+2], acc[i][j+3]};
      *(float4*)(Part + ob + (size_t)(ty*8+i)*128 + tx*8 + j) = o;
    }
}

// ---------------------------------------------------------------------------
// PhiT V partial
// ---------------------------------------------------------------------------
__global__ __launch_bounds__(256) void phiTv_partial(
    const float* __restrict__ Phi, const float* __restrict__ V,
    float* __restrict__ Part)
{
  const int bh = blockIdx.x, sp = blockIdx.y, tid = threadIdx.x;
  const int b = bh >> 3, h = bh & 7;
  __shared__ alignas(16) float Ps[16][128];
  __shared__ alignas(16) float Vs[16][64];
  const int ty = tid >> 3, tx = tid & 7;
  float acc[4][8];
#pragma unroll
  for (int i = 0; i < 4; ++i)
#pragma unroll
    for (int j = 0; j < 8; ++j) acc[i][j] = 0.f;
  const int lrow = tid >> 4, lcol = (tid & 15) << 3;
  const int vrow = tid >> 3, vcol = (tid & 7) << 3;
  for (int n0 = sp*512; n0 < sp*512 + 512; n0 += 16) {
    float4 p0 = *(const float4*)(Phi + ((size_t)bh*N_ + n0 + lrow)*M_ + lcol);
    float4 p1 = *(const float4*)(Phi + ((size_t)bh*N_ + n0 + lrow)*M_ + lcol + 4);
    *(float4*)&Ps[lrow][lcol]   = p0;
    *(float4*)&Ps[lrow][lcol+4] = p1;
    if (tid < 128) {
      float4 v0 = *(const float4*)(V + ((size_t)(b*N_) + n0 + vrow)*512 + h*64 + vcol);
      float4 v1 = *(const float4*)(V + ((size_t)(b*N_) + n0 + vrow)*512 + h*64 + vcol + 4);
      *(float4*)&Vs[vrow][vcol]   = v0;
      *(float4*)&Vs[vrow][vcol+4] = v1;
    }
    __syncthreads();
#pragma unroll
    for (int kk = 0; kk < 16; ++kk) {
      float4 av = *(const float4*)&Ps[kk][ty*4];
      float4 bv0 = *(const float4*)&Vs[kk][tx*8];
      float4 bv1 = *(const float4*)&Vs[kk][tx*8+4];
      float a[4] = {av.x, av.y, av.z, av.w};
      float b[8] = {bv0.x, bv0.y, bv0.z, bv0.w, bv1.x, bv1.y, bv1.z, bv1.w};
#pragma unroll
      for (int i = 0; i < 4; ++i)
#pragma unroll
        for (int j = 0; j < 8; ++j) acc[i][j] = fmaf(a[i], b[j], acc[i][j]);
    }
    __syncthreads();
  }
  const size_t ob = ((size_t)sp*64 + bh) * 8192;
#pragma unroll
  for (int i = 0; i < 4; ++i)
#pragma unroll
    for (int j = 0; j < 8; j += 4) {
      float4 o = {acc[i][j], acc[i][j+1], acc[i][j+2], acc[i][j+3]};
      *(float4*)(Part + ob + (size_t)(ty*4+i)*64 + tx*8 + j) = o;
    }
}

// ---------------------------------------------------------------------------
__global__ __launch_bounds__(256) void reduce4_kernel(
    const float* __restrict__ part, float* __restrict__ out, int n, size_t cs)
{
  const int i = blockIdx.x * 256 + threadIdx.x;
  if (i < n) out[i] = (part[i] + part[cs + i]) + (part[2*cs + i] + part[3*cs + i]);
}

// ---------------------------------------------------------------------------
// yy partials: yyp[ch*64 + b*8 + h] = sum over rows n0..n0+63 of v^2 for head h.
// Fully coalesced float4 row reads; grid (8 b, 32 chunks).
// ---------------------------------------------------------------------------
__global__ __launch_bounds__(256) void yy_partial(
    const float* __restrict__ V, float* __restrict__ yyp)
{
  const int b = blockIdx.x, ch = blockIdx.y;
  const int tid = threadIdx.x;
  const int tx = tid & 127, rg = tid >> 7;
  const int n0 = ch << 6;
  float s = 0.f;
  for (int r = rg; r < 64; r += 2) {
    float4 v = *(const float4*)(V + ((size_t)(b * N_) + n0 + r) * 512 + tx * 4);
    s = fmaf(v.x, v.x, s); s = fmaf(v.y, v.y, s);
    s = fmaf(v.z, v.z, s); s = fmaf(v.w, v.w, s);
  }
  __shared__ float red[256];
  red[tid] = s;
  __syncthreads();
  if (tid < 8) {  // tid = h; sum 32 contributors (16 cols x 2 row-groups)
    float t = 0.f;
    for (int j = 0; j < 16; ++j) t += red[tid * 16 + j] + red[128 + tid * 16 + j];
    yyp[ch * 64 + b * 8 + tid] = t;
  }
}

// ---------------------------------------------------------------------------
// Blocked batched Cholesky (NB=16), 256 threads, XOR-swizzled LDS.
// ---------------------------------------------------------------------------
#define EL(i,j) As[(((i) << 7) | ((j) ^ ((i) & 31)))]

__global__ __launch_bounds__(256) void chol4_kernel(
    const float* __restrict__ Gk, const float* __restrict__ Go, const float* __restrict__ Cq,
    float* __restrict__ Lk, float* __restrict__ Lo, float* __restrict__ LTq, float* __restrict__ LTk,
    float* __restrict__ ldbuf, float* __restrict__ Dinvb)
{
  __shared__ float As[128*128];
  const int bh = blockIdx.x, which = blockIdx.y, tid = threadIdx.x;
  const float* G1; const float* G2 = nullptr; float* Lout;
  if (which == 0)      { G1 = Gk; Lout = Lk;  }
  else if (which == 1) { G1 = Go; Lout = Lo;  }
  else if (which == 2) { G1 = Go; G2 = Cq; Lout = LTq; }
  else                 { G1 = Go; G2 = Gk; Lout = LTk; }
  const size_t base = (size_t)bh * 16384;
  for (int t = tid; t < 16384; t += 256) {
    float v = G1[base + t];
    if (G2) v = fmaf(5.f, G2[base + t], v);
    const int i = t >> 7, j = t & 127;
    if (i == j) v += 0.01f;
    EL(i, j) = v;
  }
  __syncthreads();

  float ldacc = 0.f;
  for (int kb = 0; kb < 8; ++kb) {
    const int k0 = kb << 4;
    const int rbase = k0 + 16;
    const int R = 128 - rbase;
    float Dg[16][16];
    float dinv[16];
    if (tid < 128) {
#pragma unroll
      for (int j = 0; j < 16; ++j)
#pragma unroll
        for (int p = 0; p < 16; ++p) if (p <= j) Dg[j][p] = EL(k0 + j, k0 + p);
#pragma unroll
      for (int kk = 0; kk < 16; ++kk) {
        const float d = sqrtf(Dg[kk][kk]);
        Dg[kk][kk] = d;
        const float di = 1.f / d;
        dinv[kk] = di;
#pragma unroll
        for (int r = 0; r < 16; ++r) if (r > kk) Dg[r][kk] *= di;
#pragma unroll
        for (int r = 0; r < 16; ++r) if (r > kk)
#pragma unroll
          for (int c2 = 0; c2 < 16; ++c2) if (c2 > kk && c2 <= r)
            Dg[r][c2] = fmaf(-Dg[r][kk], Dg[c2][kk], Dg[r][c2]);
      }
      if (tid == 0) {
#pragma unroll
        for (int kk = 0; kk < 16; ++kk) ldacc += logf(Dg[kk][kk]);
#pragma unroll
        for (int j = 0; j < 16; ++j)
#pragma unroll
          for (int p = 0; p < 16; ++p) if (p <= j) EL(k0 + j, k0 + p) = Dg[j][p];
      }
    }
    if (tid < R) {
      const int r = rbase + tid;
      float xr[16];
#pragma unroll
      for (int p = 0; p < 16; ++p) xr[p] = EL(r, k0 + p);
#pragma unroll
      for (int j = 0; j < 16; ++j) {
        float s = xr[j];
#pragma unroll
        for (int p = 0; p < 16; ++p) if (p < j) s = fmaf(-Dg[j][p], xr[p], s);
        xr[j] = s * dinv[j];
      }
#pragma unroll
      for (int p = 0; p < 16; ++p) EL(r, k0 + p) = xr[p];
    }
    __syncthreads();
    if (R > 0) {
      const int Rt = R >> 2;
      const int T = (Rt * (Rt + 1)) >> 1;
      for (int idx = tid; idx < T; idx += 256) {
        int ti = (int)((sqrtf(8.f * (float)idx + 1.f) - 1.f) * 0.5f);
        while (((ti + 1) * (ti + 2)) / 2 <= idx) ++ti;
        while ((ti * (ti + 1)) / 2 > idx) --ti;
        const int tj = idx - (ti * (ti + 1)) / 2;
        const int i0 = rbase + (ti << 2), j0 = rbase + (tj << 2);
        float Li[4][16], Lj[4][16], cc[4][4];
#pragma unroll
        for (int a = 0; a < 4; ++a)
#pragma unroll
          for (int p = 0; p < 16; ++p) Li[a][p] = EL(i0 + a, k0 + p);
#pragma unroll
        for (int bq2 = 0; bq2 < 4; ++bq2)
#pragma unroll
          for (int p = 0; p < 16; ++p) Lj[bq2][p] = EL(j0 + bq2, k0 + p);
#pragma unroll
        for (int a = 0; a < 4; ++a)
#pragma unroll
          for (int bq2 = 0; bq2 < 4; ++bq2) cc[a][bq2] = EL(i0 + a, j0 + bq2);
#pragma unroll
        for (int p = 0; p < 16; ++p)
#pragma unroll
          for (int a = 0; a < 4; ++a)
#pragma unroll
            for (int bq2 = 0; bq2 < 4; ++bq2)
              cc[a][bq2] = fmaf(-Li[a][p], Lj[bq2][p], cc[a][bq2]);
#pragma unroll
        for (int a = 0; a < 4; ++a)
#pragma unroll
          for (int bq2 = 0; bq2 < 4; ++bq2) EL(i0 + a, j0 + bq2) = cc[a][bq2];
      }
    }
    __syncthreads();
  }
  for (int t = tid; t < 16384; t += 256) {
    const int i = t >> 7, j = t & 127;
    Lout[base + t] = (j <= i) ? EL(i, j) : EL(j, i);
  }
  if (tid < 128) Dinvb[(size_t)which * 8192 + bh * 128 + tid] = 1.f / EL(tid, tid);
  if (tid == 0) ldbuf[which * 64 + bh] = 2.f * ldacc;
}

// ---------------------------------------------------------------------------
// Blocked batched cho_solve (NB=16), 256 threads.
// ---------------------------------------------------------------------------
__global__ __launch_bounds__(256) void solve5_kernel(
    const float* __restrict__ Lk, const float* __restrict__ Lo,
    const float* __restrict__ LTq, const float* __restrict__ LTk,
    const float* __restrict__ Dinvb,
    const float* __restrict__ PkTv, const float* __restrict__ PhiTy,
    const float* __restrict__ Cq, const float* __restrict__ Gk,
    float* __restrict__ Z1, float* __restrict__ Aoi,
    float* __restrict__ Z2, float* __restrict__ Wq2, float* __restrict__ Wk2)
{
  __shared__ alignas(16) float Xs[128][128];
  __shared__ alignas(16) float Lp[128][16];
  __shared__ float di[128];
  const int bh = blockIdx.x, which = blockIdx.y, tid = threadIdx.x;
  const float* Lsrc; const float* Bsrc; float* Out; int nr; int mat;
  if (which == 0)      { Lsrc = Lk;  Bsrc = PkTv;    Out = Z1;  nr = 64;  mat = 0; }
  else if (which == 1) { Lsrc = Lo;  Bsrc = nullptr; Out = Aoi; nr = 128; mat = 1; }
  else if (which == 2) { Lsrc = LTq; Bsrc = PhiTy;   Out = Z2;  nr = 64;  mat = 2; }
  else if (which == 3) { Lsrc = LTq; Bsrc = Cq;      Out = Wq2; nr = 128; mat = 2; }
  else                 { Lsrc = LTk; Bsrc = Gk;      Out = Wk2; nr = 128; mat = 3; }
  const size_t baseL = (size_t)bh * 16384;
  const size_t baseB = (size_t)bh * 128 * (size_t)nr;
  const int sh = (nr == 64) ? 6 : 7, mk = nr - 1;
  if (Bsrc) {
    for (int t = tid; t < 128 * nr; t += 256) Xs[t >> sh][t & mk] = Bsrc[baseB + t];
  } else {
    for (int t = tid; t < 16384; t += 256)
      Xs[t >> 7][t & 127] = ((t >> 7) == (t & 127)) ? 1.f : 0.f;
  }
  if (tid < 128) di[tid] = Dinvb[(size_t)mat * 8192 + bh * 128 + tid];
  const int c0 = (nr == 128) ? ((tid & 31) << 2) : ((tid & 15) << 2);
  const int rg = (nr == 128) ? (tid >> 5) : (tid >> 4);
  const int rstride = (nr == 128) ? 8 : 16;
  __syncthreads();
  // ===== forward: L y = b =====
  for (int kb = 0; kb < 8; ++kb) {
    const int k0 = kb << 4;
    const int nrow = 128 - k0;
    for (int t = tid; t < nrow * 4; t += 256) {
      const int pr = t >> 2, pc = (t & 3) << 2;
      *(float4*)&Lp[pr][pc] = *(const float4*)(Lsrc + baseL + (size_t)(k0 + pr) * 128 + k0 + pc);
    }
    __syncthreads();
    if (tid < nr) {
      float xb[16];
#pragma unroll
      for (int j = 0; j < 16; ++j) {
        float s = Xs[k0 + j][tid];
#pragma unroll
        for (int p = 0; p < 16; ++p) if (p < j) s = fmaf(-Lp[j][p], xb[p], s);
        xb[j] = s * di[k0 + j];
        Xs[k0 + j][tid] = xb[j];
      }
    }
    __syncthreads();
    if (k0 + 16 < 128) {
      float4 xb4[16];
#pragma unroll
      for (int p = 0; p < 16; ++p) xb4[p] = *(const float4*)&Xs[k0 + p][c0];
      for (int r = k0 + 16 + rg; r < 128; r += rstride) {
        float4 xv = *(const float4*)&Xs[r][c0];
#pragma unroll
        for (int p = 0; p < 16; ++p) {
          const float l = Lp[r - k0][p];
          xv.x = fmaf(-l, xb4[p].x, xv.x);
          xv.y = fmaf(-l, xb4[p].y, xv.y);
          xv.z = fmaf(-l, xb4[p].z, xv.z);
          xv.w = fmaf(-l, xb4[p].w, xv.w);
        }
        *(float4*)&Xs[r][c0] = xv;
      }
    }
    __syncthreads();
  }
  // ===== backward: L^T x = y =====
  for (int kb = 7; kb >= 0; --kb) {
    const int k0 = kb << 4;
    const int nrow = k0 + 16;
    for (int t = tid; t < nrow * 4; t += 256) {
      const int pr = t >> 2, pc = (t & 3) << 2;
      *(float4*)&Lp[pr][pc] = *(const float4*)(Lsrc + baseL + (size_t)pr * 128 + k0 + pc);
    }
    __syncthreads();
    if (tid < nr) {
      float xb[16];
#pragma unroll
      for (int j = 15; j >= 0; --j) {
        float s = Xs[k0 + j][tid];
#pragma unroll
        for (int p = 0; p < 16; ++p) if (p > j) s = fmaf(-Lp[k0 + j][p], xb[p], s);
        xb[j] = s * di[k0 + j];
        Xs[k0 + j][tid] = xb[j];
      }
    }
    __syncthreads();
    if (k0 > 0) {
      float4 xb4[16];
#pragma unroll
      for (int p = 0; p < 16; ++p) xb4[p] = *(const float4*)&Xs[k0 + p][c0];
      for (int r = rg; r < k0; r += rstride) {
        float4 xv = *(const float4*)&Xs[r][c0];
#pragma unroll
        for (int p = 0; p < 16; ++p) {
          const float l = Lp[r][p];
          xv.x = fmaf(-l, xb4[p].x, xv.x);
          xv.y = fmaf(-l, xb4[p].y, xv.y);
          xv.z = fmaf(-l, xb4[p].z, xv.z);
          xv.w = fmaf(-l, xb4[p].w, xv.w);
        }
        *(float4*)&Xs[r][c0] = xv;
      }
    }
    __syncthreads();
  }
  for (int t = tid; t < 128 * nr; t += 256) Out[baseB + t] = Xs[t >> sh][t & mk];
}

// ---------------------------------------------------------------------------
// mid = Z1 - 0.01 * Aoi @ Z1   (Aoi symmetric)
// ---------------------------------------------------------------------------
__global__ __launch_bounds__(256) void mid_kernel(
    const float* __restrict__ Aoi, const float* __restrict__ Z1,
    float* __restrict__ midb)
{
  __shared__ alignas(16) float Ao[128][128];
  __shared__ alignas(16) float Z[128][64];
  const int bh = blockIdx.x, tid = threadIdx.x;
  const size_t bM = (size_t)bh * 16384, bD = (size_t)bh * 8192;
  for (int t4 = tid; t4 < 4096; t4 += 256) {
    const int r = t4 >> 5, c4 = (t4 & 31) << 2;
    *(float4*)&Ao[r][c4] = *(const float4*)(Aoi + bM + (size_t)r*128 + c4);
  }
  for (int t4 = tid; t4 < 2048; t4 += 256) {
    const int r = t4 >> 4, c4 = (t4 & 15) << 2;
    *(float4*)&Z[r][c4] = *(const float4*)(Z1 + bD + (size_t)r*64 + c4);
  }
  __syncthreads();
  const int ty = tid >> 4, tx = tid & 15;
  float acc[8][4];
#pragma unroll
  for (int i = 0; i < 8; ++i)
#pragma unroll
    for (int j = 0; j < 4; ++j) acc[i][j] = 0.f;
  for (int kk = 0; kk < 128; ++kk) {
    float4 a0 = *(const float4*)&Ao[kk][ty*8];
    float4 a1 = *(const float4*)&Ao[kk][ty*8+4];
    float4 bv = *(const float4*)&Z[kk][tx*4];
    float a[8] = {a0.x, a0.y, a0.z, a0.w, a1.x, a1.y, a1.z, a1.w};
    float b[4] = {bv.x, bv.y, bv.z, bv.w};
#pragma unroll
    for (int i = 0; i < 8; ++i)
#pragma unroll
      for (int j = 0; j < 4; ++j) acc[i][j] = fmaf(a[i], b[j], acc[i][j]);
  }
#pragma unroll
  for (int i = 0; i < 8; ++i) {
    const int r = ty*8 + i, c = tx*4;
    float4 o;
    o.x = Z[r][c+0] - 0.01f*acc[i][0];
    o.y = Z[r][c+1] - 0.01f*acc[i][1];
    o.z = Z[r][c+2] - 0.01f*acc[i][2];
    o.w = Z[r][c+3] - 0.01f*acc[i][3];
    *(float4*)(midb + bD + (size_t)r*64 + c) = o;
  }
}

// ---------------------------------------------------------------------------
// Pq = Cq @ Wq2 ; Pk = Gk @ Wk2   (A operand symmetric)
// ---------------------------------------------------------------------------
__global__ __launch_bounds__(256) void pmat_kernel(
    const float* __restrict__ Cq, const float* __restrict__ Wq2,
    const float* __restrict__ Gk, const float* __restrict__ Wk2,
    float* __restrict__ Pq, float* __restrict__ Pk)
{
  __shared__ alignas(16) float Am[128][128];
  __shared__ alignas(16) float Bm[128][128];
  const int bh = blockIdx.x, which = blockIdx.y, tid = threadIdx.x;
  const float* Ap = which ? Gk : Cq;
  const float* Bp = which ? Wk2 : Wq2;
  float* Op = which ? Pk : Pq;
  const size_t base = (size_t)bh * 16384;
  for (int t4 = tid; t4 < 4096; t4 += 256) {
    const int r = t4 >> 5, c4 = (t4 & 31) << 2;
    *(float4*)&Am[r][c4] = *(const float4*)(Ap + base + (size_t)r*128 + c4);
    *(float4*)&Bm[r][c4] = *(const float4*)(Bp + base + (size_t)r*128 + c4);
  }
  __syncthreads();
  const int ty = tid >> 4, tx = tid & 15;
  float acc[8][8];
#pragma unroll
  for (int i = 0; i < 8; ++i)
#pragma unroll
    for (int j = 0; j < 8; ++j) acc[i][j] = 0.f;
  for (int kk = 0; kk < 128; ++kk) {
    float4 av0 = *(const float4*)&Am[kk][ty*8];
    float4 av1 = *(const float4*)&Am[kk][ty*8+4];
    float4 bv0 = *(const float4*)&Bm[kk][tx*8];
    float4 bv1 = *(const float4*)&Bm[kk][tx*8+4];
    float a[8] = {av0.x, av0.y, av0.z, av0.w, av1.x, av1.y, av1.z, av1.w};
    float b[8] = {bv0.x, bv0.y, bv0.z, bv0.w, bv1.x, bv1.y, bv1.z, bv1.w};
#pragma unroll
    for (int i = 0; i < 8; ++i)
#pragma unroll
      for (int j = 0; j < 8; ++j) acc[i][j] = fmaf(a[i], b[j], acc[i][j]);
  }
#pragma unroll
  for (int i = 0; i < 8; ++i)
#pragma unroll
    for (int j = 0; j < 8; j += 4) {
      float4 o = {acc[i][j], acc[i][j+1], acc[i][j+2], acc[i][j+3]};
      *(float4*)(Op + base + (size_t)(ty*8+i)*128 + tx*8 + j) = o;
    }
}

// ---------------------------------------------------------------------------
__global__ __launch_bounds__(256) void scalars_kernel(
    const float* __restrict__ Aoi, const float* __restrict__ Cq, const float* __restrict__ Gk,
    const float* __restrict__ Pq, const float* __restrict__ Pk, const float* __restrict__ Wk2,
    const float* __restrict__ PhiTy, const float* __restrict__ Z2,
    const float* __restrict__ yyp, const float* __restrict__ ldb,
    float* __restrict__ regp)
{
  const int bh = blockIdx.x, tid = threadIdx.x;
  const size_t b0 = (size_t)bh * 16384, b1 = (size_t)bh * 8192;
  double aoCq=0, aoGk=0, aoPq=0, aoPk=0, wkGk=0, trCq=0, trGk=0, trPq=0, trPk=0, s1=0;
  for (int t = tid; t < 16384; t += 256) {
    const double ao = Aoi[b0+t], cq = Cq[b0+t], gk = Gk[b0+t];
    const double pq = Pq[b0+t], pk = Pk[b0+t], wk = Wk2[b0+t];
    aoCq += ao*cq; aoGk += ao*gk; aoPq += ao*pq; aoPk += ao*pk; wkGk += wk*gk;
    if (t % 129 == 0) { trCq += cq; trGk += gk; trPq += pq; trPk += pk; }
  }
  for (int t = tid; t < 8192; t += 256) s1 += (double)PhiTy[b1+t] * (double)Z2[b1+t];
  __shared__ double red[256];
  double vals[10] = {aoCq, aoGk, aoPq, aoPk, wkGk, trCq, trGk, trPq, trPk, s1};
  double tot[10];
  for (int vv = 0; vv < 10; ++vv) {
    red[tid] = vals[vv];
    __syncthreads();
    for (int st = 128; st > 0; st >>= 1) {
      if (tid < st) red[tid] += red[tid+st];
      __syncthreads();
    }
    tot[vv] = red[0];
    __syncthreads();
  }
  if (tid == 0) {
    const double D = 64.0, Nd = 2048.0;
    const double ldAo = ldb[64 + bh], ldTq = ldb[128 + bh], ldTk = ldb[192 + bh];
    double yv = 0.0;
    for (int c = 0; c < 32; ++c) yv += (double)yyp[c * 64 + bh];
    const double cst  = Nd * log(2.0 * 3.14159265358979323846);
    const double leps = Nd * log(0.002);
    const double datq = 500.0*yv - 2500.0*tot[9];
    const double modq = D*(500.0*tot[5] - 2500.0*tot[7] - 0.01*(500.0*tot[0] - 2500.0*tot[2]));
    const double ldq  = leps + ldTq - ldAo;
    const double LBq  = -0.5*(datq + modq + ldq + cst);
    const double datk = D*(500.0*tot[6] - 2500.0*tot[4]);
    const double modk = D*(500.0*tot[6] - 2500.0*tot[8] - 0.01*(500.0*tot[1] - 2500.0*tot[3]));
    const double ldk  = leps + ldTk - ldAo;
    const double LBk  = -0.5*(datk + modk + ldk + cst);
    regp[bh] = (float)(-(LBq + LBk) / 64.0);
  }
}

__global__ void regfinal_kernel(const float* __restrict__ regp, float* __restrict__ outp)
{
  __shared__ float red[64];
  const int tid = threadIdx.x;
  red[tid] = regp[tid];
  __syncthreads();
  for (int st = 32; st > 0; st >>= 1) {
    if (tid < st) red[tid] += red[tid+st];
    __syncthreads();
  }
  if (tid == 0) outp[0] = red[0];
}

// ---------------------------------------------------------------------------
// y = Phi_q @ mid -> emitted directly as bf16 hi/lo (feeds final gemm_mfma).
// ---------------------------------------------------------------------------
__global__ __launch_bounds__(256) void y_kernel(
    const float* __restrict__ Phi, const float* __restrict__ midb,
    unsigned short* __restrict__ Yhi, unsigned short* __restrict__ Ylo)
{
  __shared__ alignas(16) float Ps[128][128];
  __shared__ alignas(16) float Ms[128][64];
  const int blk = blockIdx.x;
  const int bh = blk >> 4, nt = blk & 15;
  const int b = bh >> 3, h = bh & 7;
  const int n0 = nt << 7;
  const int tid = threadIdx.x;
  for (int t4 = tid; t4 < 4096; t4 += 256) {
    const int r = t4 >> 5, c4 = (t4 & 31) << 2;
    *(float4*)&Ps[r][c4] = *(const float4*)(Phi + ((size_t)bh*N_ + n0 + r)*M_ + c4);
  }
  for (int t4 = tid; t4 < 2048; t4 += 256) {
    const int r = t4 >> 4, c4 = (t4 & 15) << 2;
    *(float4*)&Ms[r][c4] = *(const float4*)(midb + (size_t)bh*8192 + (size_t)r*64 + c4);
  }
  __syncthreads();
  const int ty = tid >> 4, tx = tid & 15;
  float acc[8][4];
#pragma unroll
  for (int i = 0; i < 8; ++i)
#pragma unroll
    for (int j = 0; j < 4; ++j) acc[i][j] = 0.f;
  for (int kk = 0; kk < 128; ++kk) {
    float4 bv = *(const float4*)&Ms[kk][tx*4];
    float b4[4] = {bv.x, bv.y, bv.z, bv.w};
#pragma unroll
    for (int i = 0; i < 8; ++i) {
      const float a = Ps[ty*8+i][kk];
      acc[i][0] = fmaf(a, b4[0], acc[i][0]);
      acc[i][1] = fmaf(a, b4[1], acc[i][1]);
      acc[i][2] = fmaf(a, b4[2], acc[i][2]);
      acc[i][3] = fmaf(a, b4[3], acc[i][3]);
    }
  }
#pragma unroll
  for (int i = 0; i < 8; ++i) {
    const size_t addr = ((size_t)(b*N_) + n0 + ty*8 + i)*512 + h*64 + tx*4;
    ushort4 hv, lv;
    hv.x = f2bf(acc[i][0]); lv.x = f2bf(acc[i][0] - bf2f(hv.x));
    hv.y = f2bf(acc[i][1]); lv.y = f2bf(acc[i][1] - bf2f(hv.y));
    hv.z = f2bf(acc[i][2]); lv.z = f2bf(acc[i][2] - bf2f(hv.z));
    hv.w = f2bf(acc[i][3]); lv.w = f2bf(acc[i][3] - bf2f(hv.w));
    *(ushort4*)(Yhi + addr) = hv;
    *(ushort4*)(Ylo + addr) = lv;
  }
}

// ---------------------------------------------------------------------------
extern "C" void kernel_launch(void* const* d_in, const int* in_sizes, int n_in,
                              void* d_out, int out_size, void* d_ws, size_t ws_size,
                              hipStream_t stream)
{
  const float* x     = (const float*)d_in[0];
  const float* mask  = (const float*)d_in[1];
  const float* Wq    = (const float*)d_in[2];
  const float* bq    = (const float*)d_in[3];
  const float* Wk    = (const float*)d_in[4];
  const float* bk    = (const float*)d_in[5];
  const float* Wv    = (const float*)d_in[6];
  const float* bv    = (const float*)d_in[7];
  const float* Wx0   = (const float*)d_in[8];
  const float* bx0   = (const float*)d_in[9];
  const float* Wo    = (const float*)d_in[10];
  const float* bo    = (const float*)d_in[11];
  const float* omega = (const float*)d_in[12];
  const float* brff  = (const float*)d_in[13];
  float* outp = (float*)d_out;

  float* W_ = (float*)d_ws;
  size_t off = 0;
  auto take = [&](size_t n) -> float* { float* p = W_ + off; off += n; return p; };
  const size_t SZ_BNH = (size_t)8*2048*512;    // 8,388,608
  const size_t SZ_PHI = (size_t)64*2048*128;   // 16,777,216
  const size_t SZ_MM  = (size_t)64*128*128;    // 1,048,576
  const size_t SZ_MD  = (size_t)64*128*64;     //   524,288

  float* tmp  = take(SZ_BNH);   // q/k/x0 heads (fp32)
  float* vb   = take(SZ_BNH);
  float* Phi  = take(SZ_PHI);
  unsigned short* Xhi = (unsigned short*)take(SZ_BNH/2);   // bf16 x-hi (later y-hi)
  unsigned short* Xlo = (unsigned short*)take(SZ_BNH/2);   // bf16 x-lo (later y-lo)
  unsigned short* Wsp = (unsigned short*)take((size_t)5*524288/2); // 5x (hi + lo)
  float* Gk   = take(SZ_MM);
  float* Go   = take(SZ_MM);
  float* Cq   = take(SZ_MM);
  float* Lk   = take(SZ_MM);
  float* Lo   = take(SZ_MM);
  float* LTq  = take(SZ_MM);
  float* LTk  = take(SZ_MM);
  float* Aoi  = take(SZ_MM);
  float* Wq2  = take(SZ_MM);
  float* Wk2  = take(SZ_MM);
  float* Pq   = take(SZ_MM);
  float* Pk   = take(SZ_MM);
  float* PkTv = take(SZ_MD);
  float* PhiTy= take(SZ_MD);
  float* Z1   = take(SZ_MD);
  float* Z2   = take(SZ_MD);
  float* midb = take(SZ_MD);
  float* Part = take(4*SZ_MM);
  float* Dinv = take(4*64*128);
  float* yyp  = take(2048);
  float* ldb  = take(256);
  float* regp = take(64);
  (void)ws_size; (void)in_sizes; (void)n_in; (void)out_size;

  unsigned short* WH0 = Wsp + 0*524288;            // Wq hi
  unsigned short* WL0 = Wsp + 0*524288 + 262144;   // Wq lo
  unsigned short* WH1 = Wsp + 1*524288;            // Wk
  unsigned short* WL1 = Wsp + 1*524288 + 262144;
  unsigned short* WH2 = Wsp + 2*524288;            // Wv
  unsigned short* WL2 = Wsp + 2*524288 + 262144;
  unsigned short* WH3 = Wsp + 3*524288;            // Wx0
  unsigned short* WL3 = Wsp + 3*524288 + 262144;
  unsigned short* WH4 = Wsp + 4*524288;            // Wo
  unsigned short* WL4 = Wsp + 4*524288 + 262144;

  // split inputs to bf16 hi/lo
  split_kernel<<<8192, 256, 0, stream>>>(x, Xhi, Xlo, (int)SZ_BNH);
  split_kernel<<<256, 256, 0, stream>>>(Wq,  WH0, WL0, 262144);
  split_kernel<<<256, 256, 0, stream>>>(Wk,  WH1, WL1, 262144);
  split_kernel<<<256, 256, 0, stream>>>(Wv,  WH2, WL2, 262144);
  split_kernel<<<256, 256, 0, stream>>>(Wx0, WH3, WL3, 262144);
  split_kernel<<<256, 256, 0, stream>>>(Wo,  WH4, WL4, 262144);

  // x0 path -> Go
  gemm_mfma<<<512, 256, 0, stream>>>(Xhi, Xlo, WH3, WL3, bx0, nullptr, tmp);
  rff_kernel<<<4096, 128, 0, stream>>>(tmp, omega, brff, mask, Phi);
  gram_partial<<<dim3(64,4), 256, 0, stream>>>(Phi, Part);
  reduce4_kernel<<<4096, 256, 0, stream>>>(Part, Go, 1048576, (size_t)1048576);
  // k path -> Gk, PkTv
  gemm_mfma<<<512, 256, 0, stream>>>(Xhi, Xlo, WH1, WL1, bk, nullptr, tmp);
  rff_kernel<<<4096, 128, 0, stream>>>(tmp, omega, brff, mask, Phi);
  gram_partial<<<dim3(64,4), 256, 0, stream>>>(Phi, Part);
  reduce4_kernel<<<4096, 256, 0, stream>>>(Part, Gk, 1048576, (size_t)1048576);
  gemm_mfma<<<512, 256, 0, stream>>>(Xhi, Xlo, WH2, WL2, bv, mask, vb);
  phiTv_partial<<<dim3(64,4), 256, 0, stream>>>(Phi, vb, Part);
  reduce4_kernel<<<2048, 256, 0, stream>>>(Part, PkTv, 524288, (size_t)524288);
  yy_partial<<<dim3(8,32), 256, 0, stream>>>(vb, yyp);
  // q path -> Cq, PhiTy
  gemm_mfma<<<512, 256, 0, stream>>>(Xhi, Xlo, WH0, WL0, bq, nullptr, tmp);
  rff_kernel<<<4096, 128, 0, stream>>>(tmp, omega, brff, mask, Phi);
  gram_partial<<<dim3(64,4), 256, 0, stream>>>(Phi, Part);
  reduce4_kernel<<<4096, 256, 0, stream>>>(Part, Cq, 1048576, (size_t)1048576);
  phiTv_partial<<<dim3(64,4), 256, 0, stream>>>(Phi, vb, Part);
  reduce4_kernel<<<2048, 256, 0, stream>>>(Part, PhiTy, 524288, (size_t)524288);
  // batched linear algebra
  chol4_kernel<<<dim3(64,4), 256, 0, stream>>>(Gk, Go, Cq, Lk, Lo, LTq, LTk, ldb, Dinv);
  solve5_kernel<<<dim3(64,5), 256, 0, stream>>>(Lk, Lo, LTq, LTk, Dinv, PkTv, PhiTy, Cq, Gk,
                                                Z1, Aoi, Z2, Wq2, Wk2);
  mid_kernel<<<64, 256, 0, stream>>>(Aoi, Z1, midb);
  pmat_kernel<<<dim3(64,2), 256, 0, stream>>>(Cq, Wq2, Gk, Wk2, Pq, Pk);
  scalars_kernel<<<64, 256, 0, stream>>>(Aoi, Cq, Gk, Pq, Pk, Wk2, PhiTy, Z2, yyp, ldb, regp);
  regfinal_kernel<<<1, 64, 0, stream>>>(regp, outp + SZ_BNH);
  // output path: y emitted directly as bf16 hi/lo, project with Wo
  y_kernel<<<1024, 256, 0, stream>>>(Phi, midb, Xhi, Xlo);
  gemm_mfma<<<512, 256, 0, stream>>>(Xhi, Xlo, WH4, WL4, bo, nullptr, outp);
}